// Round 14
// baseline (298.670 us; speedup 1.0000x reference)
//
#include <hip/hip_runtime.h>

namespace {

constexpr int kHW  = 128 * 128;
constexpr int kCH  = 256;
constexpr int kHID = 10;
constexpr int kB   = 8;

typedef __attribute__((ext_vector_type(8))) short bf16x8;
typedef __attribute__((ext_vector_type(4))) float f32x4;

// leaf (per 2-leaf class): 80 rows bf16 + seg table 20 quads x 4 fp32
constexpr int kSegOffL   = 80 * 512;
constexpr int kLdsBytesL = kSegOffL + 20 * 4 * 4;

// fused uplow+full: 128 A-rows + sideU [80][11] + sideF [48][11] + xch [8][16][20]
// After GEMM2 the A-row region [0, 61440) is reused as the h+cv stage:
//   4 waves x 120 rows x 32 px x 4 B = 61440 B (per-phase: 32 of the wave's 64 px)
constexpr int kSideOffU2 = 128 * 512;                    // 65536
constexpr int kSideOffF2 = kSideOffU2 + 80 * 11 * 4;     // 69056
constexpr int kXchOff    = kSideOffF2 + 48 * 11 * 4;     // 71168
constexpr int kLdsBytesUF = kXchOff + 8 * 16 * 20 * 4;   // 81408

__device__ __forceinline__ float sigm(float x) {
    return __builtin_amdgcn_rcpf(1.0f + __expf(-x));
}
__device__ __forceinline__ float tanh_(float x) {
    return 1.0f - 2.0f * __builtin_amdgcn_rcpf(__expf(2.0f * x) + 1.0f);
}
__device__ __forceinline__ unsigned short bf16b(float f) {
    unsigned u = __float_as_uint(f);
    return (unsigned short)((u + 0x7FFFu + ((u >> 16) & 1u)) >> 16);  // RNE (staging only)
}
// 8 fp32 -> bf16x8 via 4x v_cvt_pk_bf16_f32 (RNE)
__device__ __forceinline__ bf16x8 cvt8(const float* v) {
    union { unsigned u[4]; bf16x8 h; } r;
    #pragma unroll
    for (int i = 0; i < 4; ++i)
        asm("v_cvt_pk_bf16_f32 %0, %1, %2"
            : "=v"(r.u[i]) : "v"(v[2 * i]), "v"(v[2 * i + 1]));
    return r.h;
}

// issue 4 cols x 8 channels of strided fp32 loads for K-step `step` from `base`
#define LOADF(base, step)                                                  \
    { const float* p_ = (base) + (step) * 32 * kHW;                        \
      _Pragma("unroll") for (int c_ = 0; c_ < 4; ++c_)                     \
      _Pragma("unroll") for (int j_ = 0; j_ < 8; ++j_)                     \
          nf[c_][j_] = p_[c_ * 16 + j_ * kHW]; }

#define CVT4()                                                             \
    { _Pragma("unroll") for (int c_ = 0; c_ < 4; ++c_) bc[c_] = cvt8(nf[c_]); }

// ---------------- Kernel 1 (MFMA): leaf cells (R11 verbatim) ----------------
// 20 triples t, rows t*4+{0:i,1:g,2:o,3:pad}; 5 M-tiles.
// bid = group*24 + cls*8 + tlow: same-tile blocks differ by 8 -> same XCD L2.
__global__ __launch_bounds__(256, 3) void k_leaf_mfma(
    const float* __restrict__ p_fea,   // [B, CH, HW]
    const float* __restrict__ seg_p,   // [B, 7, HW]
    const float* __restrict__ W_leaf,  // [6, 30, 257]
    float* __restrict__ out)           // [18, B, 10, HW]
{
    extern __shared__ char smem[];
    const int tid   = threadIdx.x;
    const int bid   = blockIdx.x;
    const int group = bid / 24;                // tile/8
    const int rem   = bid - group * 24;
    const int cls   = rem >> 3;                // 0..2
    const int tile  = group * 8 + (rem & 7);   // 0..511

    for (int idx = tid; idx < 2 * 30 * 257; idx += 256) {
        const int np   = idx / 7710;
        const int rrem = idx - np * 7710;
        const int orow = rrem / 257;
        const int c    = rrem - orow * 257;
        const int g    = orow / 10;            // 0=i,1=o,2=g (reference order)
        const int q    = orow - g * 10;
        const int slot = (g == 0) ? 0 : (g == 1 ? 2 : 1);   // (i,g,o,pad)
        const int t    = np * 10 + q;
        const float v  = W_leaf[(cls * 2 + np) * 7710 + rrem];
        if (c == 256) {
            ((float*)(smem + kSegOffL))[t * 4 + slot] = v;
        } else {
            const int row  = t * 4 + slot;
            const int byte = row * 512 + ((2 * c) ^ ((row & 7) << 4));
            *(unsigned short*)(smem + byte) = bf16b(v);
        }
    }
    for (int i = tid; i < 20 * 128; i += 256) {   // zero pad rows (slot 3)
        const int t = i >> 7, d = i & 127;
        *(unsigned*)(smem + (t * 4 + 3) * 512 + d * 4) = 0u;
    }
    if (tid < 20) ((float*)(smem + kSegOffL))[tid * 4 + 3] = 0.f;
    __syncthreads();

    const int w  = tid >> 6;
    const int ln = tid & 63;
    const int lr = ln & 15;
    const int lg = ln >> 4;

    const int b    = tile >> 6;
    const int hw0  = (tile & 63) * 256;
    const int col0 = hw0 + w * 64 + lr;
    const float* bbase = p_fea + b * kCH * kHW + lg * 8 * kHW + col0;

    f32x4 acc[5][4];
    #pragma unroll
    for (int m = 0; m < 5; ++m)
        #pragma unroll
        for (int c = 0; c < 4; ++c) {
            acc[m][c][0] = 0.f; acc[m][c][1] = 0.f;
            acc[m][c][2] = 0.f; acc[m][c][3] = 0.f;
        }

    float nf[4][8];
    bf16x8 bc[4];
    LOADF(bbase, 0)
    CVT4()
    LOADF(bbase, 1)

    #pragma unroll
    for (int ks = 0; ks < 8; ++ks) {
        const int kb = (ks * 32 + lg * 8) * 2;
        #pragma unroll
        for (int m = 0; m < 5; ++m) {
            const int row = m * 16 + lr;
            const bf16x8 a = *(const bf16x8*)(
                smem + row * 512 + (kb ^ ((row & 7) << 4)));
            #pragma unroll
            for (int c = 0; c < 4; ++c)
                acc[m][c] = __builtin_amdgcn_mfma_f32_16x16x32_bf16(a, bc[c], acc[m][c], 0, 0, 0);
        }
        if (ks < 7) {
            CVT4()
            if (ks < 6) LOADF(bbase, ks + 2)
        }
    }

    #pragma unroll
    for (int m = 0; m < 5; ++m) {
        const int t = m * 4 + lg;                   // local triple < 20
        const int n = cls * 2 + t / 10;             // global leaf
        const int q = t % 10;
        const float4 sw = *(const float4*)(smem + kSegOffL + t * 16);
        const float* sp = seg_p + (b * 7 + n + 1) * kHW;
        float* oh = out + ((n * kB + b) * kHID + q) * kHW;
        float* oc = out + (((9 + n) * kB + b) * kHID + q) * kHW;
        #pragma unroll
        for (int ct = 0; ct < 4; ++ct) {
            const int px = col0 + ct * 16;
            const float sg = sp[px];
            const float ci = acc[m][ct][0] + sw.x * sg;
            const float cg = acc[m][ct][1] + sw.y * sg;
            const float co = acc[m][ct][2] + sw.z * sg;
            const float c  = sigm(ci) * tanh_(cg);
            const float h  = sigm(co) * tanh_(c);
            oh[px] = h;
            oc[px] = c;
        }
    }
}

// ---------------- Kernel 2 (MFMA): fused up + low + full tree cells ----------------
// A-rows 0..79: uplow quads (up t=0..9: {i,g,f,pad}; low t=10..19: {i,g,o,f})
// A-rows 80..127: full quads t=0..9: {i,g,o,f}; t=10,11 pad.
// full's h-coupling (h_sum = 2*low_h) folded x2 into sideF for i,g,o (not f).
// Epilogue (R14): TWO px-column phases; per phase, stage children h (rows 0..59)
// AND children c (rows 60..119) for 32 px via global_load_lds (2 rows per call:
// lanes 0..31 -> row 2k, lanes 32..63 -> row 2k+1), then all epilogue reads hit LDS.
__global__ __launch_bounds__(256, 2) void k_uplow_full_mfma(
    const float* __restrict__ h_fea,   // [B, CH, HW]
    const float* __restrict__ f_fea,   // [B, CH, HW]
    const float* __restrict__ seg_h,   // [B, 3, HW]
    const float* __restrict__ seg_f,   // [B, 2, HW]
    const float* __restrict__ W_up,    const float* __restrict__ Wf_up,
    const float* __restrict__ W_low,   const float* __restrict__ Wf_low,
    const float* __restrict__ W_full,  const float* __restrict__ Wf_full,
    float* __restrict__ out)
{
    extern __shared__ char smem[];
    const int tid = threadIdx.x;

    for (int idx = tid; idx < 128 * 267; idx += 256) {
        const int row = idx / 267;
        const int c   = idx - row * 267;
        float v = 0.f;
        if (row < 80) {
            const int t = row >> 2, slot = row & 3;
            if (t < 10) {
                if      (slot == 0) v = W_up[t * 267 + c];
                else if (slot == 1) v = W_up[(20 + t) * 267 + c];
                else if (slot == 2) v = Wf_up[t * 267 + c];
            } else {
                const int q = t - 10;
                if      (slot == 0) v = W_low[q * 267 + c];
                else if (slot == 1) v = W_low[(20 + q) * 267 + c];
                else if (slot == 2) v = W_low[(10 + q) * 267 + c];
                else                v = Wf_low[q * 267 + c];
            }
        } else {
            const int r2 = row - 80;
            const int t = r2 >> 2, slot = r2 & 3;
            if (t < 10) {
                if      (slot == 0) v = W_full[t * 267 + c];
                else if (slot == 1) v = W_full[(20 + t) * 267 + c];
                else if (slot == 2) v = W_full[(10 + t) * 267 + c];
                else                v = Wf_full[t * 267 + c];
                if (c >= 257 && slot < 3) v *= 2.0f;   // h_sum = 2*low_h
            }
        }
        if (c < 256) {
            const int byte = row * 512 + ((2 * c) ^ ((row & 7) << 4));
            *(unsigned short*)(smem + byte) = bf16b(v);
        } else if (row < 80) {
            ((float*)(smem + kSideOffU2))[row * 11 + (c - 256)] = v;
        } else {
            ((float*)(smem + kSideOffF2))[(row - 80) * 11 + (c - 256)] = v;
        }
    }
    __syncthreads();

    const int w  = tid >> 6;
    const int ln = tid & 63;
    const int lr = ln & 15;
    const int lg = ln >> 4;
    const float* sideU = (const float*)(smem + kSideOffU2);
    const float* sideF = (const float*)(smem + kSideOffF2);
    float* xch = (float*)(smem + kXchOff) + w * 320 + lr * 20;

    const int tix  = blockIdx.x;               // 512 tiles of 256 px
    const int b    = tix >> 6;
    const int hw0  = (tix & 63) * 256;
    const int col0 = hw0 + w * 64 + lr;
    const float* bbaseH = h_fea + b * kCH * kHW + lg * 8 * kHW + col0;
    const float* bbaseF = f_fea + b * kCH * kHW + lg * 8 * kHW + col0;

    f32x4 acc[5][4];
    #pragma unroll
    for (int m = 0; m < 5; ++m)
        #pragma unroll
        for (int c = 0; c < 4; ++c) {
            acc[m][c][0] = 0.f; acc[m][c][1] = 0.f;
            acc[m][c][2] = 0.f; acc[m][c][3] = 0.f;
        }
    f32x4 accF[3][4];
    #pragma unroll
    for (int m = 0; m < 3; ++m)
        #pragma unroll
        for (int c = 0; c < 4; ++c) {
            accF[m][c][0] = 0.f; accF[m][c][1] = 0.f;
            accF[m][c][2] = 0.f; accF[m][c][3] = 0.f;
        }

    float nf[4][8];
    bf16x8 bc[4];

    // ---- GEMM 1: uplow vs h_fea ----
    LOADF(bbaseH, 0)
    CVT4()
    LOADF(bbaseH, 1)
    #pragma unroll
    for (int ks = 0; ks < 8; ++ks) {
        const int kb = (ks * 32 + lg * 8) * 2;
        #pragma unroll
        for (int m = 0; m < 5; ++m) {
            const int row = m * 16 + lr;
            const bf16x8 a = *(const bf16x8*)(
                smem + row * 512 + (kb ^ ((row & 7) << 4)));
            #pragma unroll
            for (int c = 0; c < 4; ++c)
                acc[m][c] = __builtin_amdgcn_mfma_f32_16x16x32_bf16(a, bc[c], acc[m][c], 0, 0, 0);
        }
        if (ks < 7) {
            CVT4()
            if (ks < 6) LOADF(bbaseH, ks + 2)
        }
    }

    // ---- GEMM 2: full vs f_fea (rows 80..127) ----
    LOADF(bbaseF, 0)
    CVT4()
    LOADF(bbaseF, 1)
    #pragma unroll
    for (int ks = 0; ks < 8; ++ks) {
        const int kb = (ks * 32 + lg * 8) * 2;
        #pragma unroll
        for (int m = 0; m < 3; ++m) {
            const int row = 80 + m * 16 + lr;
            const bf16x8 a = *(const bf16x8*)(
                smem + row * 512 + (kb ^ ((row & 7) << 4)));
            #pragma unroll
            for (int c = 0; c < 4; ++c)
                accF[m][c] = __builtin_amdgcn_mfma_f32_16x16x32_bf16(a, bc[c], accF[m][c], 0, 0, 0);
        }
        if (ks < 7) {
            CVT4()
            if (ks < 6) LOADF(bbaseF, ks + 2)
        }
    }

    // ---- two-phase epilogue: stage h (rows 0..59) + cv (rows 60..119) per 32-px half ----
    __syncthreads();   // everyone done reading A-rows
    char* stBase = smem + w * 15360;           // 120 rows x 32 px x 4 B per wave
    const float* stR = (const float*)stBase;
    const int rowHalf = ln >> 5;               // lanes 0..31 -> row 2k, 32..63 -> 2k+1
    const int colL    = ln & 31;

    #pragma unroll
    for (int phase = 0; phase < 2; ++phase) {
        if (phase == 1) {
            // phase-0 LDS reads complete before overwriting the stage
            asm volatile("s_waitcnt lgkmcnt(0)" ::: "memory");
            __builtin_amdgcn_sched_barrier(0);
        }
        const int ctBase = phase * 32;
        #pragma unroll
        for (int k = 0; k < 60; ++k) {
            const int row = 2 * k + rowHalf;   // 0..119
            int gi;
            if (row < 60) {
                gi = ((row / 10) * kB + b) * kHID + (row % 10);          // h: slices 0..5
            } else {
                const int r2 = row - 60;
                gi = (((r2 / 10) + 9) * kB + b) * kHID + (r2 % 10);      // cv: slices 9..14
            }
            const float* g = out + (size_t)gi * kHW + hw0 + w * 64 + ctBase + colL;
            __builtin_amdgcn_global_load_lds(
                (const __attribute__((address_space(1))) unsigned*)g,
                (__attribute__((address_space(3))) unsigned*)(stBase + k * 256),
                4, 0, 0);
        }
        // seg prefetch under the stage's vmcnt shadow
        float sUv[2], sLv[2], sFv[2];
        #pragma unroll
        for (int cti = 0; cti < 2; ++cti) {
            const int px = col0 + (phase * 2 + cti) * 16;
            sUv[cti] = seg_h[(b * 3 + 1) * kHW + px];
            sLv[cti] = seg_h[(b * 3 + 2) * kHW + px];
            sFv[cti] = seg_f[(b * 2 + 1) * kHW + px];
        }
        asm volatile("s_waitcnt vmcnt(0)" ::: "memory");
        __builtin_amdgcn_sched_barrier(0);

        #pragma unroll
        for (int cti = 0; cti < 2; ++cti) {
            const int ct  = phase * 2 + cti;
            const int px  = col0 + ct * 16;
            const int ixl = lr + cti * 16;     // column within this phase's 32
            const float sU = sUv[cti], sL = sLv[cti], sF = sFv[cti];

            float hsU[10], hsL[10];
            #pragma unroll
            for (int j = 0; j < 10; ++j) {
                hsU[j] = stR[(0 * 10 + j) * 32 + ixl] + stR[(1 * 10 + j) * 32 + ixl]
                       + stR[(2 * 10 + j) * 32 + ixl] + stR[(3 * 10 + j) * 32 + ixl];
                hsL[j] = stR[(4 * 10 + j) * 32 + ixl] + stR[(5 * 10 + j) * 32 + ixl];
            }

            float ucv[3] = {0.f, 0.f, 0.f};

            #pragma unroll
            for (int m = 0; m < 5; ++m) {
                const int t = m * 4 + lg;
                if (t < 10) {
                    float ai = acc[m][ct][0] + sideU[(t * 4 + 0) * 11] * sU;
                    float ag = acc[m][ct][1] + sideU[(t * 4 + 1) * 11] * sU;
                    const float pf = acc[m][ct][2] + sideU[(t * 4 + 2) * 11] * sU;
                    float cs = 0.f;
                    #pragma unroll
                    for (int n = 0; n < 4; ++n) {
                        float fh = pf;
                        #pragma unroll
                        for (int j = 0; j < 10; ++j)
                            fh = fmaf(sideU[(t * 4 + 2) * 11 + 1 + j],
                                      stR[(n * 10 + j) * 32 + ixl], fh);
                        const float cv = stR[(60 + n * 10 + t) * 32 + ixl];
                        cs = fmaf(sigm(fh), cv, cs);
                    }
                    #pragma unroll
                    for (int j = 0; j < 10; ++j) {
                        ai = fmaf(sideU[(t * 4 + 0) * 11 + 1 + j], hsU[j], ai);
                        ag = fmaf(sideU[(t * 4 + 1) * 11 + 1 + j], hsU[j], ag);
                    }
                    const float uc = sigm(ai) * tanh_(ag) + cs;
                    out[((15 * kB + b) * kHID + t) * kHW + px] = uc;
                    if (m < 3) ucv[m] = uc;
                } else {
                    const int q = t - 10;
                    float ai = acc[m][ct][0] + sideU[(t * 4 + 0) * 11] * sL;
                    float ag = acc[m][ct][1] + sideU[(t * 4 + 1) * 11] * sL;
                    float ao = acc[m][ct][2] + sideU[(t * 4 + 2) * 11] * sL;
                    const float pf = acc[m][ct][3] + sideU[(t * 4 + 3) * 11] * sL;
                    float cs = 0.f;
                    #pragma unroll
                    for (int n = 4; n < 6; ++n) {
                        float fh = pf;
                        #pragma unroll
                        for (int j = 0; j < 10; ++j)
                            fh = fmaf(sideU[(t * 4 + 3) * 11 + 1 + j],
                                      stR[(n * 10 + j) * 32 + ixl], fh);
                        const float cv = stR[(60 + n * 10 + q) * 32 + ixl];
                        cs = fmaf(sigm(fh), cv, cs);
                    }
                    #pragma unroll
                    for (int j = 0; j < 10; ++j) {
                        ai = fmaf(sideU[(t * 4 + 0) * 11 + 1 + j], hsL[j], ai);
                        ag = fmaf(sideU[(t * 4 + 1) * 11 + 1 + j], hsL[j], ag);
                        ao = fmaf(sideU[(t * 4 + 2) * 11 + 1 + j], hsL[j], ao);
                    }
                    const float lcv = sigm(ai) * tanh_(ag) + cs;
                    const float lhv = sigm(ao) * tanh_(lcv);
                    out[((6 * kB + b) * kHID + q) * kHW + px]  = lhv;
                    out[((7 * kB + b) * kHID + q) * kHW + px]  = lhv;
                    out[((16 * kB + b) * kHID + q) * kHW + px] = lcv;
                    xch[q]      = lhv;
                    xch[10 + q] = lcv;
                }
            }

            asm volatile("s_waitcnt lgkmcnt(0)" ::: "memory");
            __builtin_amdgcn_sched_barrier(0);

            float lhx[10];
            #pragma unroll
            for (int j = 0; j < 10; ++j) lhx[j] = xch[j];

            #pragma unroll
            for (int mf = 0; mf < 3; ++mf) {
                const int t = mf * 4 + lg;
                if (t < 10) {
                    float ai = accF[mf][ct][0] + sideF[(t * 4 + 0) * 11] * sF;
                    float ag = accF[mf][ct][1] + sideF[(t * 4 + 1) * 11] * sF;
                    float ao = accF[mf][ct][2] + sideF[(t * 4 + 2) * 11] * sF;
                    float fh = accF[mf][ct][3] + sideF[(t * 4 + 3) * 11] * sF;
                    #pragma unroll
                    for (int j = 0; j < 10; ++j) {
                        ai = fmaf(sideF[(t * 4 + 0) * 11 + 1 + j], lhx[j], ai);
                        ag = fmaf(sideF[(t * 4 + 1) * 11 + 1 + j], lhx[j], ag);
                        ao = fmaf(sideF[(t * 4 + 2) * 11 + 1 + j], lhx[j], ao);
                        fh = fmaf(sideF[(t * 4 + 3) * 11 + 1 + j], lhx[j], fh);
                    }
                    const float lcx = xch[10 + t];
                    const float cf = sigm(ai) * tanh_(ag) + sigm(fh) * (ucv[mf] + lcx);
                    const float hv = sigm(ao) * tanh_(cf);
                    out[((8 * kB + b) * kHID + t) * kHW + px]  = hv;
                    out[((17 * kB + b) * kHID + t) * kHW + px] = cf;
                }
            }
        }
    }
}

}  // namespace

extern "C" void kernel_launch(void* const* d_in, const int* in_sizes, int n_in,
                              void* d_out, int out_size, void* d_ws, size_t ws_size,
                              hipStream_t stream) {
    const float* seg_p   = (const float*)d_in[0];
    const float* seg_h   = (const float*)d_in[1];
    const float* seg_f   = (const float*)d_in[2];
    const float* p_fea   = (const float*)d_in[3];
    const float* h_fea   = (const float*)d_in[4];
    const float* f_fea   = (const float*)d_in[5];
    const float* W_leaf  = (const float*)d_in[6];
    const float* W_up    = (const float*)d_in[7];
    const float* Wf_up   = (const float*)d_in[8];
    const float* W_low   = (const float*)d_in[9];
    const float* Wf_low  = (const float*)d_in[10];
    const float* W_full  = (const float*)d_in[11];
    const float* Wf_full = (const float*)d_in[12];
    float* out = (float*)d_out;

    // fused kernel uses >64 KB dynamic LDS
    (void)hipFuncSetAttribute(reinterpret_cast<const void*>(k_uplow_full_mfma),
                              hipFuncAttributeMaxDynamicSharedMemorySize, kLdsBytesUF);

    hipLaunchKernelGGL(k_leaf_mfma, dim3(3 * 512), dim3(256), kLdsBytesL, stream,
                       p_fea, seg_p, W_leaf, out);
    hipLaunchKernelGGL(k_uplow_full_mfma, dim3(512), dim3(256), kLdsBytesUF, stream,
                       h_fea, f_fea, seg_h, seg_f,
                       W_up, Wf_up, W_low, Wf_low, W_full, Wf_full, out);
}

// Round 15
// 257.041 us; speedup vs baseline: 1.1620x; 1.1620x over previous
//
#include <hip/hip_runtime.h>

namespace {

constexpr int kHW  = 128 * 128;
constexpr int kCH  = 256;
constexpr int kHID = 10;
constexpr int kB   = 8;

typedef __attribute__((ext_vector_type(8))) short bf16x8;
typedef __attribute__((ext_vector_type(4))) float f32x4;

// leaf (per 2-leaf class): 80 rows bf16 + seg table 20 quads x 4 fp32
constexpr int kSegOffL   = 80 * 512;
constexpr int kLdsBytesL = kSegOffL + 20 * 4 * 4;

// fused uplow+full: 128 A-rows + sideU [80][11] + sideF [48][11] + xch [8][16][20]
// After GEMM2 the A-row region [0, 61440) is reused as children-h stage:
//   4 waves x 60 rows x 256 B = 61440 B (h[n][j][px] per wave's 64 px)
constexpr int kSideOffU2 = 128 * 512;                    // 65536
constexpr int kSideOffF2 = kSideOffU2 + 80 * 11 * 4;     // 69056
constexpr int kXchOff    = kSideOffF2 + 48 * 11 * 4;     // 71168
constexpr int kLdsBytesUF = kXchOff + 8 * 16 * 20 * 4;   // 81408

__device__ __forceinline__ float sigm(float x) {
    return __builtin_amdgcn_rcpf(1.0f + __expf(-x));
}
__device__ __forceinline__ float tanh_(float x) {
    return 1.0f - 2.0f * __builtin_amdgcn_rcpf(__expf(2.0f * x) + 1.0f);
}
__device__ __forceinline__ unsigned short bf16b(float f) {
    unsigned u = __float_as_uint(f);
    return (unsigned short)((u + 0x7FFFu + ((u >> 16) & 1u)) >> 16);  // RNE (staging only)
}
// 8 fp32 -> bf16x8 via 4x v_cvt_pk_bf16_f32 (RNE)
__device__ __forceinline__ bf16x8 cvt8(const float* v) {
    union { unsigned u[4]; bf16x8 h; } r;
    #pragma unroll
    for (int i = 0; i < 4; ++i)
        asm("v_cvt_pk_bf16_f32 %0, %1, %2"
            : "=v"(r.u[i]) : "v"(v[2 * i]), "v"(v[2 * i + 1]));
    return r.h;
}

// issue 4 cols x 8 channels of strided fp32 loads for K-step `step` from `base`
#define LOADF(base, step)                                                  \
    { const float* p_ = (base) + (step) * 32 * kHW;                        \
      _Pragma("unroll") for (int c_ = 0; c_ < 4; ++c_)                     \
      _Pragma("unroll") for (int j_ = 0; j_ < 8; ++j_)                     \
          nf[c_][j_] = p_[c_ * 16 + j_ * kHW]; }

#define CVT4()                                                             \
    { _Pragma("unroll") for (int c_ = 0; c_ < 4; ++c_) bc[c_] = cvt8(nf[c_]); }

// ---------------- Kernel 1 (MFMA): leaf cells (R11 verbatim) ----------------
// 20 triples t, rows t*4+{0:i,1:g,2:o,3:pad}; 5 M-tiles.
// bid = group*24 + cls*8 + tlow: same-tile blocks differ by 8 -> same XCD L2.
__global__ __launch_bounds__(256, 3) void k_leaf_mfma(
    const float* __restrict__ p_fea,   // [B, CH, HW]
    const float* __restrict__ seg_p,   // [B, 7, HW]
    const float* __restrict__ W_leaf,  // [6, 30, 257]
    float* __restrict__ out)           // [18, B, 10, HW]
{
    extern __shared__ char smem[];
    const int tid   = threadIdx.x;
    const int bid   = blockIdx.x;
    const int group = bid / 24;                // tile/8
    const int rem   = bid - group * 24;
    const int cls   = rem >> 3;                // 0..2
    const int tile  = group * 8 + (rem & 7);   // 0..511

    for (int idx = tid; idx < 2 * 30 * 257; idx += 256) {
        const int np   = idx / 7710;
        const int rrem = idx - np * 7710;
        const int orow = rrem / 257;
        const int c    = rrem - orow * 257;
        const int g    = orow / 10;            // 0=i,1=o,2=g (reference order)
        const int q    = orow - g * 10;
        const int slot = (g == 0) ? 0 : (g == 1 ? 2 : 1);   // (i,g,o,pad)
        const int t    = np * 10 + q;
        const float v  = W_leaf[(cls * 2 + np) * 7710 + rrem];
        if (c == 256) {
            ((float*)(smem + kSegOffL))[t * 4 + slot] = v;
        } else {
            const int row  = t * 4 + slot;
            const int byte = row * 512 + ((2 * c) ^ ((row & 7) << 4));
            *(unsigned short*)(smem + byte) = bf16b(v);
        }
    }
    for (int i = tid; i < 20 * 128; i += 256) {   // zero pad rows (slot 3)
        const int t = i >> 7, d = i & 127;
        *(unsigned*)(smem + (t * 4 + 3) * 512 + d * 4) = 0u;
    }
    if (tid < 20) ((float*)(smem + kSegOffL))[tid * 4 + 3] = 0.f;
    __syncthreads();

    const int w  = tid >> 6;
    const int ln = tid & 63;
    const int lr = ln & 15;
    const int lg = ln >> 4;

    const int b    = tile >> 6;
    const int hw0  = (tile & 63) * 256;
    const int col0 = hw0 + w * 64 + lr;
    const float* bbase = p_fea + b * kCH * kHW + lg * 8 * kHW + col0;

    f32x4 acc[5][4];
    #pragma unroll
    for (int m = 0; m < 5; ++m)
        #pragma unroll
        for (int c = 0; c < 4; ++c) {
            acc[m][c][0] = 0.f; acc[m][c][1] = 0.f;
            acc[m][c][2] = 0.f; acc[m][c][3] = 0.f;
        }

    float nf[4][8];
    bf16x8 bc[4];
    LOADF(bbase, 0)
    CVT4()
    LOADF(bbase, 1)

    #pragma unroll
    for (int ks = 0; ks < 8; ++ks) {
        const int kb = (ks * 32 + lg * 8) * 2;
        #pragma unroll
        for (int m = 0; m < 5; ++m) {
            const int row = m * 16 + lr;
            const bf16x8 a = *(const bf16x8*)(
                smem + row * 512 + (kb ^ ((row & 7) << 4)));
            #pragma unroll
            for (int c = 0; c < 4; ++c)
                acc[m][c] = __builtin_amdgcn_mfma_f32_16x16x32_bf16(a, bc[c], acc[m][c], 0, 0, 0);
        }
        if (ks < 7) {
            CVT4()
            if (ks < 6) LOADF(bbase, ks + 2)
        }
    }

    #pragma unroll
    for (int m = 0; m < 5; ++m) {
        const int t = m * 4 + lg;                   // local triple < 20
        const int n = cls * 2 + t / 10;             // global leaf
        const int q = t % 10;
        const float4 sw = *(const float4*)(smem + kSegOffL + t * 16);
        const float* sp = seg_p + (b * 7 + n + 1) * kHW;
        float* oh = out + ((n * kB + b) * kHID + q) * kHW;
        float* oc = out + (((9 + n) * kB + b) * kHID + q) * kHW;
        #pragma unroll
        for (int ct = 0; ct < 4; ++ct) {
            const int px = col0 + ct * 16;
            const float sg = sp[px];
            const float ci = acc[m][ct][0] + sw.x * sg;
            const float cg = acc[m][ct][1] + sw.y * sg;
            const float co = acc[m][ct][2] + sw.z * sg;
            const float c  = sigm(ci) * tanh_(cg);
            const float h  = sigm(co) * tanh_(c);
            oh[px] = h;
            oc[px] = c;
        }
    }
}

// ---------------- Kernel 2 (MFMA): fused up + low + full tree cells ----------------
// A-rows 0..79: uplow quads (up t=0..9: {i,g,f,pad}; low t=10..19: {i,g,o,f})
// A-rows 80..127: full quads t=0..9: {i,g,o,f}; t=10,11 pad.
// full's h-coupling (h_sum = 2*low_h) folded x2 into sideF for i,g,o (not f).
// Epilogue (R13 + seg-hoist): children h staged via global_load_lds into freed
// A-row region; the 12 seg loads are issued under the same vmcnt shadow.
__global__ __launch_bounds__(256, 2) void k_uplow_full_mfma(
    const float* __restrict__ h_fea,   // [B, CH, HW]
    const float* __restrict__ f_fea,   // [B, CH, HW]
    const float* __restrict__ seg_h,   // [B, 3, HW]
    const float* __restrict__ seg_f,   // [B, 2, HW]
    const float* __restrict__ W_up,    const float* __restrict__ Wf_up,
    const float* __restrict__ W_low,   const float* __restrict__ Wf_low,
    const float* __restrict__ W_full,  const float* __restrict__ Wf_full,
    float* __restrict__ out)
{
    extern __shared__ char smem[];
    const int tid = threadIdx.x;

    for (int idx = tid; idx < 128 * 267; idx += 256) {
        const int row = idx / 267;
        const int c   = idx - row * 267;
        float v = 0.f;
        if (row < 80) {
            const int t = row >> 2, slot = row & 3;
            if (t < 10) {
                if      (slot == 0) v = W_up[t * 267 + c];
                else if (slot == 1) v = W_up[(20 + t) * 267 + c];
                else if (slot == 2) v = Wf_up[t * 267 + c];
            } else {
                const int q = t - 10;
                if      (slot == 0) v = W_low[q * 267 + c];
                else if (slot == 1) v = W_low[(20 + q) * 267 + c];
                else if (slot == 2) v = W_low[(10 + q) * 267 + c];
                else                v = Wf_low[q * 267 + c];
            }
        } else {
            const int r2 = row - 80;
            const int t = r2 >> 2, slot = r2 & 3;
            if (t < 10) {
                if      (slot == 0) v = W_full[t * 267 + c];
                else if (slot == 1) v = W_full[(20 + t) * 267 + c];
                else if (slot == 2) v = W_full[(10 + t) * 267 + c];
                else                v = Wf_full[t * 267 + c];
                if (c >= 257 && slot < 3) v *= 2.0f;   // h_sum = 2*low_h
            }
        }
        if (c < 256) {
            const int byte = row * 512 + ((2 * c) ^ ((row & 7) << 4));
            *(unsigned short*)(smem + byte) = bf16b(v);
        } else if (row < 80) {
            ((float*)(smem + kSideOffU2))[row * 11 + (c - 256)] = v;
        } else {
            ((float*)(smem + kSideOffF2))[(row - 80) * 11 + (c - 256)] = v;
        }
    }
    __syncthreads();

    const int w  = tid >> 6;
    const int ln = tid & 63;
    const int lr = ln & 15;
    const int lg = ln >> 4;
    const float* sideU = (const float*)(smem + kSideOffU2);
    const float* sideF = (const float*)(smem + kSideOffF2);
    float* xch = (float*)(smem + kXchOff) + w * 320 + lr * 20;

    const int tix  = blockIdx.x;               // 512 tiles of 256 px
    const int b    = tix >> 6;
    const int hw0  = (tix & 63) * 256;
    const int col0 = hw0 + w * 64 + lr;
    const float* bbaseH = h_fea + b * kCH * kHW + lg * 8 * kHW + col0;
    const float* bbaseF = f_fea + b * kCH * kHW + lg * 8 * kHW + col0;

    f32x4 acc[5][4];
    #pragma unroll
    for (int m = 0; m < 5; ++m)
        #pragma unroll
        for (int c = 0; c < 4; ++c) {
            acc[m][c][0] = 0.f; acc[m][c][1] = 0.f;
            acc[m][c][2] = 0.f; acc[m][c][3] = 0.f;
        }
    f32x4 accF[3][4];
    #pragma unroll
    for (int m = 0; m < 3; ++m)
        #pragma unroll
        for (int c = 0; c < 4; ++c) {
            accF[m][c][0] = 0.f; accF[m][c][1] = 0.f;
            accF[m][c][2] = 0.f; accF[m][c][3] = 0.f;
        }

    float nf[4][8];
    bf16x8 bc[4];

    // ---- GEMM 1: uplow vs h_fea ----
    LOADF(bbaseH, 0)
    CVT4()
    LOADF(bbaseH, 1)
    #pragma unroll
    for (int ks = 0; ks < 8; ++ks) {
        const int kb = (ks * 32 + lg * 8) * 2;
        #pragma unroll
        for (int m = 0; m < 5; ++m) {
            const int row = m * 16 + lr;
            const bf16x8 a = *(const bf16x8*)(
                smem + row * 512 + (kb ^ ((row & 7) << 4)));
            #pragma unroll
            for (int c = 0; c < 4; ++c)
                acc[m][c] = __builtin_amdgcn_mfma_f32_16x16x32_bf16(a, bc[c], acc[m][c], 0, 0, 0);
        }
        if (ks < 7) {
            CVT4()
            if (ks < 6) LOADF(bbaseH, ks + 2)
        }
    }

    // ---- GEMM 2: full vs f_fea (rows 80..127) ----
    LOADF(bbaseF, 0)
    CVT4()
    LOADF(bbaseF, 1)
    #pragma unroll
    for (int ks = 0; ks < 8; ++ks) {
        const int kb = (ks * 32 + lg * 8) * 2;
        #pragma unroll
        for (int m = 0; m < 3; ++m) {
            const int row = 80 + m * 16 + lr;
            const bf16x8 a = *(const bf16x8*)(
                smem + row * 512 + (kb ^ ((row & 7) << 4)));
            #pragma unroll
            for (int c = 0; c < 4; ++c)
                accF[m][c] = __builtin_amdgcn_mfma_f32_16x16x32_bf16(a, bc[c], accF[m][c], 0, 0, 0);
        }
        if (ks < 7) {
            CVT4()
            if (ks < 6) LOADF(bbaseF, ks + 2)
        }
    }

    // ---- stage children h into freed A-row LDS region (per-wave, async) ----
    __syncthreads();   // everyone done reading A-rows
    float sU4[4], sL4[4], sF4[4];
    {
        char* stBase = smem + w * 15360;   // 60 rows x 256 B per wave
        #pragma unroll
        for (int n = 0; n < 6; ++n) {
            #pragma unroll
            for (int j = 0; j < 10; ++j) {
                const float* g = out + ((n * kB + b) * kHID + j) * kHW + hw0 + w * 64 + ln;
                __builtin_amdgcn_global_load_lds(
                    (const __attribute__((address_space(1))) unsigned*)g,
                    (__attribute__((address_space(3))) unsigned*)(stBase + (n * 10 + j) * 256),
                    4, 0, 0);
            }
        }
        // seg prefetch rides the stage's latency shadow (independent VMEM loads)
        #pragma unroll
        for (int ct = 0; ct < 4; ++ct) {
            const int px = col0 + ct * 16;
            sU4[ct] = seg_h[(b * 3 + 1) * kHW + px];
            sL4[ct] = seg_h[(b * 3 + 2) * kHW + px];
            sF4[ct] = seg_f[(b * 2 + 1) * kHW + px];
        }
        asm volatile("s_waitcnt vmcnt(0)" ::: "memory");
        __builtin_amdgcn_sched_barrier(0);
    }
    const float* stW = (const float*)(smem + w * 15360);   // [60][64] fp32

    // ---- unified epilogue ----
    #pragma unroll
    for (int ct = 0; ct < 4; ++ct) {
        const int px = col0 + ct * 16;
        const int ix = lr + ct * 16;       // this lane's px within the wave's 64

        const float sU = sU4[ct];
        const float sL = sL4[ct];
        const float sF = sF4[ct];

        float hsU[10], hsL[10];
        #pragma unroll
        for (int j = 0; j < 10; ++j) {
            hsU[j] = stW[(0 * 10 + j) * 64 + ix] + stW[(1 * 10 + j) * 64 + ix]
                   + stW[(2 * 10 + j) * 64 + ix] + stW[(3 * 10 + j) * 64 + ix];
            hsL[j] = stW[(4 * 10 + j) * 64 + ix] + stW[(5 * 10 + j) * 64 + ix];
        }

        float ucv[3] = {0.f, 0.f, 0.f};

        #pragma unroll
        for (int m = 0; m < 5; ++m) {
            const int t = m * 4 + lg;
            if (t < 10) {
                float ai = acc[m][ct][0] + sideU[(t * 4 + 0) * 11] * sU;
                float ag = acc[m][ct][1] + sideU[(t * 4 + 1) * 11] * sU;
                const float pf = acc[m][ct][2] + sideU[(t * 4 + 2) * 11] * sU;
                float cs = 0.f;
                #pragma unroll
                for (int n = 0; n < 4; ++n) {
                    float fh = pf;
                    #pragma unroll
                    for (int j = 0; j < 10; ++j)
                        fh = fmaf(sideU[(t * 4 + 2) * 11 + 1 + j],
                                  stW[(n * 10 + j) * 64 + ix], fh);
                    const float cv = out[(((9 + n) * kB + b) * kHID + t) * kHW + px];
                    cs = fmaf(sigm(fh), cv, cs);
                }
                #pragma unroll
                for (int j = 0; j < 10; ++j) {
                    ai = fmaf(sideU[(t * 4 + 0) * 11 + 1 + j], hsU[j], ai);
                    ag = fmaf(sideU[(t * 4 + 1) * 11 + 1 + j], hsU[j], ag);
                }
                const float uc = sigm(ai) * tanh_(ag) + cs;
                out[((15 * kB + b) * kHID + t) * kHW + px] = uc;
                if (m < 3) ucv[m] = uc;
            } else {
                const int q = t - 10;
                float ai = acc[m][ct][0] + sideU[(t * 4 + 0) * 11] * sL;
                float ag = acc[m][ct][1] + sideU[(t * 4 + 1) * 11] * sL;
                float ao = acc[m][ct][2] + sideU[(t * 4 + 2) * 11] * sL;
                const float pf = acc[m][ct][3] + sideU[(t * 4 + 3) * 11] * sL;
                float cs = 0.f;
                #pragma unroll
                for (int n = 4; n < 6; ++n) {
                    float fh = pf;
                    #pragma unroll
                    for (int j = 0; j < 10; ++j)
                        fh = fmaf(sideU[(t * 4 + 3) * 11 + 1 + j],
                                  stW[(n * 10 + j) * 64 + ix], fh);
                    const float cv = out[(((9 + n) * kB + b) * kHID + q) * kHW + px];
                    cs = fmaf(sigm(fh), cv, cs);
                }
                #pragma unroll
                for (int j = 0; j < 10; ++j) {
                    ai = fmaf(sideU[(t * 4 + 0) * 11 + 1 + j], hsL[j], ai);
                    ag = fmaf(sideU[(t * 4 + 1) * 11 + 1 + j], hsL[j], ag);
                    ao = fmaf(sideU[(t * 4 + 2) * 11 + 1 + j], hsL[j], ao);
                }
                const float lcv = sigm(ai) * tanh_(ag) + cs;
                const float lhv = sigm(ao) * tanh_(lcv);
                out[((6 * kB + b) * kHID + q) * kHW + px]  = lhv;
                out[((7 * kB + b) * kHID + q) * kHW + px]  = lhv;
                out[((16 * kB + b) * kHID + q) * kHW + px] = lcv;
                xch[q]      = lhv;
                xch[10 + q] = lcv;
            }
        }

        asm volatile("s_waitcnt lgkmcnt(0)" ::: "memory");
        __builtin_amdgcn_sched_barrier(0);

        float lhx[10];
        #pragma unroll
        for (int j = 0; j < 10; ++j) lhx[j] = xch[j];

        #pragma unroll
        for (int mf = 0; mf < 3; ++mf) {
            const int t = mf * 4 + lg;
            if (t < 10) {
                float ai = accF[mf][ct][0] + sideF[(t * 4 + 0) * 11] * sF;
                float ag = accF[mf][ct][1] + sideF[(t * 4 + 1) * 11] * sF;
                float ao = accF[mf][ct][2] + sideF[(t * 4 + 2) * 11] * sF;
                float fh = accF[mf][ct][3] + sideF[(t * 4 + 3) * 11] * sF;
                #pragma unroll
                for (int j = 0; j < 10; ++j) {
                    ai = fmaf(sideF[(t * 4 + 0) * 11 + 1 + j], lhx[j], ai);
                    ag = fmaf(sideF[(t * 4 + 1) * 11 + 1 + j], lhx[j], ag);
                    ao = fmaf(sideF[(t * 4 + 2) * 11 + 1 + j], lhx[j], ao);
                    fh = fmaf(sideF[(t * 4 + 3) * 11 + 1 + j], lhx[j], fh);
                }
                const float lcx = xch[10 + t];
                const float cf = sigm(ai) * tanh_(ag) + sigm(fh) * (ucv[mf] + lcx);
                const float hv = sigm(ao) * tanh_(cf);
                out[((8 * kB + b) * kHID + t) * kHW + px]  = hv;
                out[((17 * kB + b) * kHID + t) * kHW + px] = cf;
            }
        }
    }
}

}  // namespace

extern "C" void kernel_launch(void* const* d_in, const int* in_sizes, int n_in,
                              void* d_out, int out_size, void* d_ws, size_t ws_size,
                              hipStream_t stream) {
    const float* seg_p   = (const float*)d_in[0];
    const float* seg_h   = (const float*)d_in[1];
    const float* seg_f   = (const float*)d_in[2];
    const float* p_fea   = (const float*)d_in[3];
    const float* h_fea   = (const float*)d_in[4];
    const float* f_fea   = (const float*)d_in[5];
    const float* W_leaf  = (const float*)d_in[6];
    const float* W_up    = (const float*)d_in[7];
    const float* Wf_up   = (const float*)d_in[8];
    const float* W_low   = (const float*)d_in[9];
    const float* Wf_low  = (const float*)d_in[10];
    const float* W_full  = (const float*)d_in[11];
    const float* Wf_full = (const float*)d_in[12];
    float* out = (float*)d_out;

    // fused kernel uses >64 KB dynamic LDS
    (void)hipFuncSetAttribute(reinterpret_cast<const void*>(k_uplow_full_mfma),
                              hipFuncAttributeMaxDynamicSharedMemorySize, kLdsBytesUF);

    hipLaunchKernelGGL(k_leaf_mfma, dim3(3 * 512), dim3(256), kLdsBytesL, stream,
                       p_fea, seg_p, W_leaf, out);
    hipLaunchKernelGGL(k_uplow_full_mfma, dim3(512), dim3(256), kLdsBytesUF, stream,
                       h_fea, f_fea, seg_h, seg_f,
                       W_up, Wf_up, W_low, Wf_low, W_full, Wf_full, out);
}

// Round 16
// 256.901 us; speedup vs baseline: 1.1626x; 1.0005x over previous
//
#include <hip/hip_runtime.h>

namespace {

constexpr int kHW  = 128 * 128;
constexpr int kCH  = 256;
constexpr int kHID = 10;
constexpr int kB   = 8;

typedef __attribute__((ext_vector_type(8))) short bf16x8;
typedef __attribute__((ext_vector_type(4))) float f32x4;

// leaf (per 2-leaf class): 80 rows bf16 + seg table 20 quads x 4 fp32
constexpr int kSegOffL   = 80 * 512;
constexpr int kLdsBytesL = kSegOffL + 20 * 4 * 4;

// fused uplow+full: 128 A-rows + sideU [80][11] + sideF [48][11] + xch [8][16][20]
// After GEMM2 the A-row region [0, 61440) is reused as children-h stage:
//   4 waves x 60 rows x 256 B = 61440 B (h[n][j][px] per wave's 64 px)
constexpr int kSideOffU2 = 128 * 512;                    // 65536
constexpr int kSideOffF2 = kSideOffU2 + 80 * 11 * 4;     // 69056
constexpr int kXchOff    = kSideOffF2 + 48 * 11 * 4;     // 71168
constexpr int kLdsBytesUF = kXchOff + 8 * 16 * 20 * 4;   // 81408

__device__ __forceinline__ float sigm(float x) {
    return __builtin_amdgcn_rcpf(1.0f + __expf(-x));
}
__device__ __forceinline__ float tanh_(float x) {
    return 1.0f - 2.0f * __builtin_amdgcn_rcpf(__expf(2.0f * x) + 1.0f);
}
__device__ __forceinline__ unsigned short bf16b(float f) {
    unsigned u = __float_as_uint(f);
    return (unsigned short)((u + 0x7FFFu + ((u >> 16) & 1u)) >> 16);  // RNE (staging only)
}
// 8 fp32 -> bf16x8 via 4x v_cvt_pk_bf16_f32 (RNE)
__device__ __forceinline__ bf16x8 cvt8(const float* v) {
    union { unsigned u[4]; bf16x8 h; } r;
    #pragma unroll
    for (int i = 0; i < 4; ++i)
        asm("v_cvt_pk_bf16_f32 %0, %1, %2"
            : "=v"(r.u[i]) : "v"(v[2 * i]), "v"(v[2 * i + 1]));
    return r.h;
}

// issue 4 cols x 8 channels of strided fp32 loads for K-step `step` from `base`
#define LOADF(base, step)                                                  \
    { const float* p_ = (base) + (step) * 32 * kHW;                        \
      _Pragma("unroll") for (int c_ = 0; c_ < 4; ++c_)                     \
      _Pragma("unroll") for (int j_ = 0; j_ < 8; ++j_)                     \
          nf[c_][j_] = p_[c_ * 16 + j_ * kHW]; }

#define CVT4()                                                             \
    { _Pragma("unroll") for (int c_ = 0; c_ < 4; ++c_) bc[c_] = cvt8(nf[c_]); }

// ---------------- Kernel 1 (MFMA): leaf cells (R11 + seg-hoist) ----------------
// 20 triples t, rows t*4+{0:i,1:g,2:o,3:pad}; 5 M-tiles.
// bid = group*24 + cls*8 + tlow: same-tile blocks differ by 8 -> same XCD L2.
// R16: the 20 per-lane seg_p loads are issued BEFORE the K-loop so they ride
// under the GEMM's latency (vmcnt ordering: oldest loads complete first).
__global__ __launch_bounds__(256, 3) void k_leaf_mfma(
    const float* __restrict__ p_fea,   // [B, CH, HW]
    const float* __restrict__ seg_p,   // [B, 7, HW]
    const float* __restrict__ W_leaf,  // [6, 30, 257]
    float* __restrict__ out)           // [18, B, 10, HW]
{
    extern __shared__ char smem[];
    const int tid   = threadIdx.x;
    const int bid   = blockIdx.x;
    const int group = bid / 24;                // tile/8
    const int rem   = bid - group * 24;
    const int cls   = rem >> 3;                // 0..2
    const int tile  = group * 8 + (rem & 7);   // 0..511

    for (int idx = tid; idx < 2 * 30 * 257; idx += 256) {
        const int np   = idx / 7710;
        const int rrem = idx - np * 7710;
        const int orow = rrem / 257;
        const int c    = rrem - orow * 257;
        const int g    = orow / 10;            // 0=i,1=o,2=g (reference order)
        const int q    = orow - g * 10;
        const int slot = (g == 0) ? 0 : (g == 1 ? 2 : 1);   // (i,g,o,pad)
        const int t    = np * 10 + q;
        const float v  = W_leaf[(cls * 2 + np) * 7710 + rrem];
        if (c == 256) {
            ((float*)(smem + kSegOffL))[t * 4 + slot] = v;
        } else {
            const int row  = t * 4 + slot;
            const int byte = row * 512 + ((2 * c) ^ ((row & 7) << 4));
            *(unsigned short*)(smem + byte) = bf16b(v);
        }
    }
    for (int i = tid; i < 20 * 128; i += 256) {   // zero pad rows (slot 3)
        const int t = i >> 7, d = i & 127;
        *(unsigned*)(smem + (t * 4 + 3) * 512 + d * 4) = 0u;
    }
    if (tid < 20) ((float*)(smem + kSegOffL))[tid * 4 + 3] = 0.f;
    __syncthreads();

    const int w  = tid >> 6;
    const int ln = tid & 63;
    const int lr = ln & 15;
    const int lg = ln >> 4;

    const int b    = tile >> 6;
    const int hw0  = (tile & 63) * 256;
    const int col0 = hw0 + w * 64 + lr;
    const float* bbase = p_fea + b * kCH * kHW + lg * 8 * kHW + col0;

    // ---- seg prefetch: issued first => completes under the GEMM's shadow ----
    float segv[5][4];
    #pragma unroll
    for (int m = 0; m < 5; ++m) {
        const int t = m * 4 + lg;
        const int n = cls * 2 + t / 10;
        const float* sp = seg_p + (b * 7 + n + 1) * kHW;
        #pragma unroll
        for (int ct = 0; ct < 4; ++ct)
            segv[m][ct] = sp[col0 + ct * 16];
    }

    f32x4 acc[5][4];
    #pragma unroll
    for (int m = 0; m < 5; ++m)
        #pragma unroll
        for (int c = 0; c < 4; ++c) {
            acc[m][c][0] = 0.f; acc[m][c][1] = 0.f;
            acc[m][c][2] = 0.f; acc[m][c][3] = 0.f;
        }

    float nf[4][8];
    bf16x8 bc[4];
    LOADF(bbase, 0)
    CVT4()
    LOADF(bbase, 1)

    #pragma unroll
    for (int ks = 0; ks < 8; ++ks) {
        const int kb = (ks * 32 + lg * 8) * 2;
        #pragma unroll
        for (int m = 0; m < 5; ++m) {
            const int row = m * 16 + lr;
            const bf16x8 a = *(const bf16x8*)(
                smem + row * 512 + (kb ^ ((row & 7) << 4)));
            #pragma unroll
            for (int c = 0; c < 4; ++c)
                acc[m][c] = __builtin_amdgcn_mfma_f32_16x16x32_bf16(a, bc[c], acc[m][c], 0, 0, 0);
        }
        if (ks < 7) {
            CVT4()
            if (ks < 6) LOADF(bbase, ks + 2)
        }
    }

    #pragma unroll
    for (int m = 0; m < 5; ++m) {
        const int t = m * 4 + lg;                   // local triple < 20
        const int n = cls * 2 + t / 10;             // global leaf
        const int q = t % 10;
        const float4 sw = *(const float4*)(smem + kSegOffL + t * 16);
        float* oh = out + ((n * kB + b) * kHID + q) * kHW;
        float* oc = out + (((9 + n) * kB + b) * kHID + q) * kHW;
        #pragma unroll
        for (int ct = 0; ct < 4; ++ct) {
            const int px = col0 + ct * 16;
            const float sg = segv[m][ct];
            const float ci = acc[m][ct][0] + sw.x * sg;
            const float cg = acc[m][ct][1] + sw.y * sg;
            const float co = acc[m][ct][2] + sw.z * sg;
            const float c  = sigm(ci) * tanh_(cg);
            const float h  = sigm(co) * tanh_(c);
            oh[px] = h;
            oc[px] = c;
        }
    }
}

// ---------------- Kernel 2 (MFMA): fused up + low + full tree cells (R15 verbatim) ----------------
// A-rows 0..79: uplow quads (up t=0..9: {i,g,f,pad}; low t=10..19: {i,g,o,f})
// A-rows 80..127: full quads t=0..9: {i,g,o,f}; t=10,11 pad.
// full's h-coupling (h_sum = 2*low_h) folded x2 into sideF for i,g,o (not f).
// Epilogue: children h staged via global_load_lds into freed A-row region;
// the 12 seg loads ride the same vmcnt shadow.
__global__ __launch_bounds__(256, 2) void k_uplow_full_mfma(
    const float* __restrict__ h_fea,   // [B, CH, HW]
    const float* __restrict__ f_fea,   // [B, CH, HW]
    const float* __restrict__ seg_h,   // [B, 3, HW]
    const float* __restrict__ seg_f,   // [B, 2, HW]
    const float* __restrict__ W_up,    const float* __restrict__ Wf_up,
    const float* __restrict__ W_low,   const float* __restrict__ Wf_low,
    const float* __restrict__ W_full,  const float* __restrict__ Wf_full,
    float* __restrict__ out)
{
    extern __shared__ char smem[];
    const int tid = threadIdx.x;

    for (int idx = tid; idx < 128 * 267; idx += 256) {
        const int row = idx / 267;
        const int c   = idx - row * 267;
        float v = 0.f;
        if (row < 80) {
            const int t = row >> 2, slot = row & 3;
            if (t < 10) {
                if      (slot == 0) v = W_up[t * 267 + c];
                else if (slot == 1) v = W_up[(20 + t) * 267 + c];
                else if (slot == 2) v = Wf_up[t * 267 + c];
            } else {
                const int q = t - 10;
                if      (slot == 0) v = W_low[q * 267 + c];
                else if (slot == 1) v = W_low[(20 + q) * 267 + c];
                else if (slot == 2) v = W_low[(10 + q) * 267 + c];
                else                v = Wf_low[q * 267 + c];
            }
        } else {
            const int r2 = row - 80;
            const int t = r2 >> 2, slot = r2 & 3;
            if (t < 10) {
                if      (slot == 0) v = W_full[t * 267 + c];
                else if (slot == 1) v = W_full[(20 + t) * 267 + c];
                else if (slot == 2) v = W_full[(10 + t) * 267 + c];
                else                v = Wf_full[t * 267 + c];
                if (c >= 257 && slot < 3) v *= 2.0f;   // h_sum = 2*low_h
            }
        }
        if (c < 256) {
            const int byte = row * 512 + ((2 * c) ^ ((row & 7) << 4));
            *(unsigned short*)(smem + byte) = bf16b(v);
        } else if (row < 80) {
            ((float*)(smem + kSideOffU2))[row * 11 + (c - 256)] = v;
        } else {
            ((float*)(smem + kSideOffF2))[(row - 80) * 11 + (c - 256)] = v;
        }
    }
    __syncthreads();

    const int w  = tid >> 6;
    const int ln = tid & 63;
    const int lr = ln & 15;
    const int lg = ln >> 4;
    const float* sideU = (const float*)(smem + kSideOffU2);
    const float* sideF = (const float*)(smem + kSideOffF2);
    float* xch = (float*)(smem + kXchOff) + w * 320 + lr * 20;

    const int tix  = blockIdx.x;               // 512 tiles of 256 px
    const int b    = tix >> 6;
    const int hw0  = (tix & 63) * 256;
    const int col0 = hw0 + w * 64 + lr;
    const float* bbaseH = h_fea + b * kCH * kHW + lg * 8 * kHW + col0;
    const float* bbaseF = f_fea + b * kCH * kHW + lg * 8 * kHW + col0;

    f32x4 acc[5][4];
    #pragma unroll
    for (int m = 0; m < 5; ++m)
        #pragma unroll
        for (int c = 0; c < 4; ++c) {
            acc[m][c][0] = 0.f; acc[m][c][1] = 0.f;
            acc[m][c][2] = 0.f; acc[m][c][3] = 0.f;
        }
    f32x4 accF[3][4];
    #pragma unroll
    for (int m = 0; m < 3; ++m)
        #pragma unroll
        for (int c = 0; c < 4; ++c) {
            accF[m][c][0] = 0.f; accF[m][c][1] = 0.f;
            accF[m][c][2] = 0.f; accF[m][c][3] = 0.f;
        }

    float nf[4][8];
    bf16x8 bc[4];

    // ---- GEMM 1: uplow vs h_fea ----
    LOADF(bbaseH, 0)
    CVT4()
    LOADF(bbaseH, 1)
    #pragma unroll
    for (int ks = 0; ks < 8; ++ks) {
        const int kb = (ks * 32 + lg * 8) * 2;
        #pragma unroll
        for (int m = 0; m < 5; ++m) {
            const int row = m * 16 + lr;
            const bf16x8 a = *(const bf16x8*)(
                smem + row * 512 + (kb ^ ((row & 7) << 4)));
            #pragma unroll
            for (int c = 0; c < 4; ++c)
                acc[m][c] = __builtin_amdgcn_mfma_f32_16x16x32_bf16(a, bc[c], acc[m][c], 0, 0, 0);
        }
        if (ks < 7) {
            CVT4()
            if (ks < 6) LOADF(bbaseH, ks + 2)
        }
    }

    // ---- GEMM 2: full vs f_fea (rows 80..127) ----
    LOADF(bbaseF, 0)
    CVT4()
    LOADF(bbaseF, 1)
    #pragma unroll
    for (int ks = 0; ks < 8; ++ks) {
        const int kb = (ks * 32 + lg * 8) * 2;
        #pragma unroll
        for (int m = 0; m < 3; ++m) {
            const int row = 80 + m * 16 + lr;
            const bf16x8 a = *(const bf16x8*)(
                smem + row * 512 + (kb ^ ((row & 7) << 4)));
            #pragma unroll
            for (int c = 0; c < 4; ++c)
                accF[m][c] = __builtin_amdgcn_mfma_f32_16x16x32_bf16(a, bc[c], accF[m][c], 0, 0, 0);
        }
        if (ks < 7) {
            CVT4()
            if (ks < 6) LOADF(bbaseF, ks + 2)
        }
    }

    // ---- stage children h into freed A-row LDS region (per-wave, async) ----
    __syncthreads();   // everyone done reading A-rows
    float sU4[4], sL4[4], sF4[4];
    {
        char* stBase = smem + w * 15360;   // 60 rows x 256 B per wave
        #pragma unroll
        for (int n = 0; n < 6; ++n) {
            #pragma unroll
            for (int j = 0; j < 10; ++j) {
                const float* g = out + ((n * kB + b) * kHID + j) * kHW + hw0 + w * 64 + ln;
                __builtin_amdgcn_global_load_lds(
                    (const __attribute__((address_space(1))) unsigned*)g,
                    (__attribute__((address_space(3))) unsigned*)(stBase + (n * 10 + j) * 256),
                    4, 0, 0);
            }
        }
        // seg prefetch rides the stage's latency shadow (independent VMEM loads)
        #pragma unroll
        for (int ct = 0; ct < 4; ++ct) {
            const int px = col0 + ct * 16;
            sU4[ct] = seg_h[(b * 3 + 1) * kHW + px];
            sL4[ct] = seg_h[(b * 3 + 2) * kHW + px];
            sF4[ct] = seg_f[(b * 2 + 1) * kHW + px];
        }
        asm volatile("s_waitcnt vmcnt(0)" ::: "memory");
        __builtin_amdgcn_sched_barrier(0);
    }
    const float* stW = (const float*)(smem + w * 15360);   // [60][64] fp32

    // ---- unified epilogue ----
    #pragma unroll
    for (int ct = 0; ct < 4; ++ct) {
        const int px = col0 + ct * 16;
        const int ix = lr + ct * 16;       // this lane's px within the wave's 64

        const float sU = sU4[ct];
        const float sL = sL4[ct];
        const float sF = sF4[ct];

        float hsU[10], hsL[10];
        #pragma unroll
        for (int j = 0; j < 10; ++j) {
            hsU[j] = stW[(0 * 10 + j) * 64 + ix] + stW[(1 * 10 + j) * 64 + ix]
                   + stW[(2 * 10 + j) * 64 + ix] + stW[(3 * 10 + j) * 64 + ix];
            hsL[j] = stW[(4 * 10 + j) * 64 + ix] + stW[(5 * 10 + j) * 64 + ix];
        }

        float ucv[3] = {0.f, 0.f, 0.f};

        #pragma unroll
        for (int m = 0; m < 5; ++m) {
            const int t = m * 4 + lg;
            if (t < 10) {
                float ai = acc[m][ct][0] + sideU[(t * 4 + 0) * 11] * sU;
                float ag = acc[m][ct][1] + sideU[(t * 4 + 1) * 11] * sU;
                const float pf = acc[m][ct][2] + sideU[(t * 4 + 2) * 11] * sU;
                float cs = 0.f;
                #pragma unroll
                for (int n = 0; n < 4; ++n) {
                    float fh = pf;
                    #pragma unroll
                    for (int j = 0; j < 10; ++j)
                        fh = fmaf(sideU[(t * 4 + 2) * 11 + 1 + j],
                                  stW[(n * 10 + j) * 64 + ix], fh);
                    const float cv = out[(((9 + n) * kB + b) * kHID + t) * kHW + px];
                    cs = fmaf(sigm(fh), cv, cs);
                }
                #pragma unroll
                for (int j = 0; j < 10; ++j) {
                    ai = fmaf(sideU[(t * 4 + 0) * 11 + 1 + j], hsU[j], ai);
                    ag = fmaf(sideU[(t * 4 + 1) * 11 + 1 + j], hsU[j], ag);
                }
                const float uc = sigm(ai) * tanh_(ag) + cs;
                out[((15 * kB + b) * kHID + t) * kHW + px] = uc;
                if (m < 3) ucv[m] = uc;
            } else {
                const int q = t - 10;
                float ai = acc[m][ct][0] + sideU[(t * 4 + 0) * 11] * sL;
                float ag = acc[m][ct][1] + sideU[(t * 4 + 1) * 11] * sL;
                float ao = acc[m][ct][2] + sideU[(t * 4 + 2) * 11] * sL;
                const float pf = acc[m][ct][3] + sideU[(t * 4 + 3) * 11] * sL;
                float cs = 0.f;
                #pragma unroll
                for (int n = 4; n < 6; ++n) {
                    float fh = pf;
                    #pragma unroll
                    for (int j = 0; j < 10; ++j)
                        fh = fmaf(sideU[(t * 4 + 3) * 11 + 1 + j],
                                  stW[(n * 10 + j) * 64 + ix], fh);
                    const float cv = out[(((9 + n) * kB + b) * kHID + q) * kHW + px];
                    cs = fmaf(sigm(fh), cv, cs);
                }
                #pragma unroll
                for (int j = 0; j < 10; ++j) {
                    ai = fmaf(sideU[(t * 4 + 0) * 11 + 1 + j], hsL[j], ai);
                    ag = fmaf(sideU[(t * 4 + 1) * 11 + 1 + j], hsL[j], ag);
                    ao = fmaf(sideU[(t * 4 + 2) * 11 + 1 + j], hsL[j], ao);
                }
                const float lcv = sigm(ai) * tanh_(ag) + cs;
                const float lhv = sigm(ao) * tanh_(lcv);
                out[((6 * kB + b) * kHID + q) * kHW + px]  = lhv;
                out[((7 * kB + b) * kHID + q) * kHW + px]  = lhv;
                out[((16 * kB + b) * kHID + q) * kHW + px] = lcv;
                xch[q]      = lhv;
                xch[10 + q] = lcv;
            }
        }

        asm volatile("s_waitcnt lgkmcnt(0)" ::: "memory");
        __builtin_amdgcn_sched_barrier(0);

        float lhx[10];
        #pragma unroll
        for (int j = 0; j < 10; ++j) lhx[j] = xch[j];

        #pragma unroll
        for (int mf = 0; mf < 3; ++mf) {
            const int t = mf * 4 + lg;
            if (t < 10) {
                float ai = accF[mf][ct][0] + sideF[(t * 4 + 0) * 11] * sF;
                float ag = accF[mf][ct][1] + sideF[(t * 4 + 1) * 11] * sF;
                float ao = accF[mf][ct][2] + sideF[(t * 4 + 2) * 11] * sF;
                float fh = accF[mf][ct][3] + sideF[(t * 4 + 3) * 11] * sF;
                #pragma unroll
                for (int j = 0; j < 10; ++j) {
                    ai = fmaf(sideF[(t * 4 + 0) * 11 + 1 + j], lhx[j], ai);
                    ag = fmaf(sideF[(t * 4 + 1) * 11 + 1 + j], lhx[j], ag);
                    ao = fmaf(sideF[(t * 4 + 2) * 11 + 1 + j], lhx[j], ao);
                    fh = fmaf(sideF[(t * 4 + 3) * 11 + 1 + j], lhx[j], fh);
                }
                const float lcx = xch[10 + t];
                const float cf = sigm(ai) * tanh_(ag) + sigm(fh) * (ucv[mf] + lcx);
                const float hv = sigm(ao) * tanh_(cf);
                out[((8 * kB + b) * kHID + t) * kHW + px]  = hv;
                out[((17 * kB + b) * kHID + t) * kHW + px] = cf;
            }
        }
    }
}

}  // namespace

extern "C" void kernel_launch(void* const* d_in, const int* in_sizes, int n_in,
                              void* d_out, int out_size, void* d_ws, size_t ws_size,
                              hipStream_t stream) {
    const float* seg_p   = (const float*)d_in[0];
    const float* seg_h   = (const float*)d_in[1];
    const float* seg_f   = (const float*)d_in[2];
    const float* p_fea   = (const float*)d_in[3];
    const float* h_fea   = (const float*)d_in[4];
    const float* f_fea   = (const float*)d_in[5];
    const float* W_leaf  = (const float*)d_in[6];
    const float* W_up    = (const float*)d_in[7];
    const float* Wf_up   = (const float*)d_in[8];
    const float* W_low   = (const float*)d_in[9];
    const float* Wf_low  = (const float*)d_in[10];
    const float* W_full  = (const float*)d_in[11];
    const float* Wf_full = (const float*)d_in[12];
    float* out = (float*)d_out;

    // fused kernel uses >64 KB dynamic LDS
    (void)hipFuncSetAttribute(reinterpret_cast<const void*>(k_uplow_full_mfma),
                              hipFuncAttributeMaxDynamicSharedMemorySize, kLdsBytesUF);

    hipLaunchKernelGGL(k_leaf_mfma, dim3(3 * 512), dim3(256), kLdsBytesL, stream,
                       p_fea, seg_p, W_leaf, out);
    hipLaunchKernelGGL(k_uplow_full_mfma, dim3(512), dim3(256), kLdsBytesUF, stream,
                       h_fea, f_fea, seg_h, seg_f,
                       W_up, Wf_up, W_low, Wf_low, W_full, Wf_full, out);
}

// Round 17
// 248.425 us; speedup vs baseline: 1.2022x; 1.0341x over previous
//
#include <hip/hip_runtime.h>

namespace {

constexpr int kHW  = 128 * 128;
constexpr int kCH  = 256;
constexpr int kHID = 10;
constexpr int kB   = 8;

typedef __attribute__((ext_vector_type(8))) short bf16x8;
typedef __attribute__((ext_vector_type(4))) float f32x4;

// leaf (per 2-leaf class): 80 rows bf16 + seg table 20 quads x 4 fp32
constexpr int kSegOffL   = 80 * 512;
constexpr int kLdsBytesL = kSegOffL + 20 * 4 * 4;

// fused uplow+full: 128 A-rows + sideU [80][11] + sideF [48][11] + xch [8][16][20]
// After GEMM2 the A-row region [0, 61440) is reused as children-h stage:
//   4 waves x 60 rows x 256 B = 61440 B (h[n][j][px] per wave's 64 px)
constexpr int kSideOffU2 = 128 * 512;                    // 65536
constexpr int kSideOffF2 = kSideOffU2 + 80 * 11 * 4;     // 69056
constexpr int kXchOff    = kSideOffF2 + 48 * 11 * 4;     // 71168
constexpr int kLdsBytesUF = kXchOff + 8 * 16 * 20 * 4;   // 81408

__device__ __forceinline__ float sigm(float x) {
    return __builtin_amdgcn_rcpf(1.0f + __expf(-x));
}
__device__ __forceinline__ float tanh_(float x) {
    return 1.0f - 2.0f * __builtin_amdgcn_rcpf(__expf(2.0f * x) + 1.0f);
}
__device__ __forceinline__ unsigned short bf16b(float f) {
    unsigned u = __float_as_uint(f);
    return (unsigned short)((u + 0x7FFFu + ((u >> 16) & 1u)) >> 16);  // RNE (staging only)
}
// 8 fp32 -> bf16x8 via 4x v_cvt_pk_bf16_f32 (RNE)
__device__ __forceinline__ bf16x8 cvt8(const float* v) {
    union { unsigned u[4]; bf16x8 h; } r;
    #pragma unroll
    for (int i = 0; i < 4; ++i)
        asm("v_cvt_pk_bf16_f32 %0, %1, %2"
            : "=v"(r.u[i]) : "v"(v[2 * i]), "v"(v[2 * i + 1]));
    return r.h;
}

// issue 4 cols x 8 channels of strided fp32 loads for K-step `step` from `base`
#define LOADF(base, step)                                                  \
    { const float* p_ = (base) + (step) * 32 * kHW;                        \
      _Pragma("unroll") for (int c_ = 0; c_ < 4; ++c_)                     \
      _Pragma("unroll") for (int j_ = 0; j_ < 8; ++j_)                     \
          nf[c_][j_] = p_[c_ * 16 + j_ * kHW]; }

#define CVT4()                                                             \
    { _Pragma("unroll") for (int c_ = 0; c_ < 4; ++c_) bc[c_] = cvt8(nf[c_]); }

// ---------------- Kernel 1 (MFMA): leaf cells (R16 + 2 tiles per block) ----------------
// 20 triples t, rows t*4+{0:i,1:g,2:o,3:pad}; 5 M-tiles.
// Block = (cls, pair); handles tiles pair and pair+256 with ONE weight stage.
// bid = pairGroup*24 + cls*8 + pairLow: same-pair cls-blocks differ by 8 -> same XCD.
__global__ __launch_bounds__(256, 3) void k_leaf_mfma(
    const float* __restrict__ p_fea,   // [B, CH, HW]
    const float* __restrict__ seg_p,   // [B, 7, HW]
    const float* __restrict__ W_leaf,  // [6, 30, 257]
    float* __restrict__ out)           // [18, B, 10, HW]
{
    extern __shared__ char smem[];
    const int tid   = threadIdx.x;
    const int bid   = blockIdx.x;              // 768 = 3 cls x 256 pairs
    const int group = bid / 24;                // pair/8
    const int rem   = bid - group * 24;
    const int cls   = rem >> 3;                // 0..2
    const int pair  = group * 8 + (rem & 7);   // 0..255

    for (int idx = tid; idx < 2 * 30 * 257; idx += 256) {
        const int np   = idx / 7710;
        const int rrem = idx - np * 7710;
        const int orow = rrem / 257;
        const int c    = rrem - orow * 257;
        const int g    = orow / 10;            // 0=i,1=o,2=g (reference order)
        const int q    = orow - g * 10;
        const int slot = (g == 0) ? 0 : (g == 1 ? 2 : 1);   // (i,g,o,pad)
        const int t    = np * 10 + q;
        const float v  = W_leaf[(cls * 2 + np) * 7710 + rrem];
        if (c == 256) {
            ((float*)(smem + kSegOffL))[t * 4 + slot] = v;
        } else {
            const int row  = t * 4 + slot;
            const int byte = row * 512 + ((2 * c) ^ ((row & 7) << 4));
            *(unsigned short*)(smem + byte) = bf16b(v);
        }
    }
    for (int i = tid; i < 20 * 128; i += 256) {   // zero pad rows (slot 3)
        const int t = i >> 7, d = i & 127;
        *(unsigned*)(smem + (t * 4 + 3) * 512 + d * 4) = 0u;
    }
    if (tid < 20) ((float*)(smem + kSegOffL))[tid * 4 + 3] = 0.f;
    __syncthreads();

    const int w  = tid >> 6;
    const int ln = tid & 63;
    const int lr = ln & 15;
    const int lg = ln >> 4;

    #pragma unroll 1
    for (int tp = 0; tp < 2; ++tp) {
        const int tile = pair + tp * 256;       // 0..511
        const int b    = tile >> 6;
        const int hw0  = (tile & 63) * 256;
        const int col0 = hw0 + w * 64 + lr;
        const float* bbase = p_fea + b * kCH * kHW + lg * 8 * kHW + col0;

        // seg prefetch: issued first => completes under the GEMM's shadow
        float segv[5][4];
        #pragma unroll
        for (int m = 0; m < 5; ++m) {
            const int t = m * 4 + lg;
            const int n = cls * 2 + t / 10;
            const float* sp = seg_p + (b * 7 + n + 1) * kHW;
            #pragma unroll
            for (int ct = 0; ct < 4; ++ct)
                segv[m][ct] = sp[col0 + ct * 16];
        }

        f32x4 acc[5][4];
        #pragma unroll
        for (int m = 0; m < 5; ++m)
            #pragma unroll
            for (int c = 0; c < 4; ++c) {
                acc[m][c][0] = 0.f; acc[m][c][1] = 0.f;
                acc[m][c][2] = 0.f; acc[m][c][3] = 0.f;
            }

        float nf[4][8];
        bf16x8 bc[4];
        LOADF(bbase, 0)
        CVT4()
        LOADF(bbase, 1)

        #pragma unroll
        for (int ks = 0; ks < 8; ++ks) {
            const int kb = (ks * 32 + lg * 8) * 2;
            #pragma unroll
            for (int m = 0; m < 5; ++m) {
                const int row = m * 16 + lr;
                const bf16x8 a = *(const bf16x8*)(
                    smem + row * 512 + (kb ^ ((row & 7) << 4)));
                #pragma unroll
                for (int c = 0; c < 4; ++c)
                    acc[m][c] = __builtin_amdgcn_mfma_f32_16x16x32_bf16(a, bc[c], acc[m][c], 0, 0, 0);
            }
            if (ks < 7) {
                CVT4()
                if (ks < 6) LOADF(bbase, ks + 2)
            }
        }

        #pragma unroll
        for (int m = 0; m < 5; ++m) {
            const int t = m * 4 + lg;                   // local triple < 20
            const int n = cls * 2 + t / 10;             // global leaf
            const int q = t % 10;
            const float4 sw = *(const float4*)(smem + kSegOffL + t * 16);
            float* oh = out + ((n * kB + b) * kHID + q) * kHW;
            float* oc = out + (((9 + n) * kB + b) * kHID + q) * kHW;
            #pragma unroll
            for (int ct = 0; ct < 4; ++ct) {
                const int px = col0 + ct * 16;
                const float sg = segv[m][ct];
                const float ci = acc[m][ct][0] + sw.x * sg;
                const float cg = acc[m][ct][1] + sw.y * sg;
                const float co = acc[m][ct][2] + sw.z * sg;
                const float c  = sigm(ci) * tanh_(cg);
                const float h  = sigm(co) * tanh_(c);
                oh[px] = h;
                oc[px] = c;
            }
        }
    }
}

// ---------------- Kernel 2 (MFMA): fused up + low + full tree cells (R16 verbatim) ----------------
// A-rows 0..79: uplow quads (up t=0..9: {i,g,f,pad}; low t=10..19: {i,g,o,f})
// A-rows 80..127: full quads t=0..9: {i,g,o,f}; t=10,11 pad.
// full's h-coupling (h_sum = 2*low_h) folded x2 into sideF for i,g,o (not f).
// Epilogue: children h staged via global_load_lds into freed A-row region;
// the 12 seg loads ride the same vmcnt shadow.
__global__ __launch_bounds__(256, 2) void k_uplow_full_mfma(
    const float* __restrict__ h_fea,   // [B, CH, HW]
    const float* __restrict__ f_fea,   // [B, CH, HW]
    const float* __restrict__ seg_h,   // [B, 3, HW]
    const float* __restrict__ seg_f,   // [B, 2, HW]
    const float* __restrict__ W_up,    const float* __restrict__ Wf_up,
    const float* __restrict__ W_low,   const float* __restrict__ Wf_low,
    const float* __restrict__ W_full,  const float* __restrict__ Wf_full,
    float* __restrict__ out)
{
    extern __shared__ char smem[];
    const int tid = threadIdx.x;

    for (int idx = tid; idx < 128 * 267; idx += 256) {
        const int row = idx / 267;
        const int c   = idx - row * 267;
        float v = 0.f;
        if (row < 80) {
            const int t = row >> 2, slot = row & 3;
            if (t < 10) {
                if      (slot == 0) v = W_up[t * 267 + c];
                else if (slot == 1) v = W_up[(20 + t) * 267 + c];
                else if (slot == 2) v = Wf_up[t * 267 + c];
            } else {
                const int q = t - 10;
                if      (slot == 0) v = W_low[q * 267 + c];
                else if (slot == 1) v = W_low[(20 + q) * 267 + c];
                else if (slot == 2) v = W_low[(10 + q) * 267 + c];
                else                v = Wf_low[q * 267 + c];
            }
        } else {
            const int r2 = row - 80;
            const int t = r2 >> 2, slot = r2 & 3;
            if (t < 10) {
                if      (slot == 0) v = W_full[t * 267 + c];
                else if (slot == 1) v = W_full[(20 + t) * 267 + c];
                else if (slot == 2) v = W_full[(10 + t) * 267 + c];
                else                v = Wf_full[t * 267 + c];
                if (c >= 257 && slot < 3) v *= 2.0f;   // h_sum = 2*low_h
            }
        }
        if (c < 256) {
            const int byte = row * 512 + ((2 * c) ^ ((row & 7) << 4));
            *(unsigned short*)(smem + byte) = bf16b(v);
        } else if (row < 80) {
            ((float*)(smem + kSideOffU2))[row * 11 + (c - 256)] = v;
        } else {
            ((float*)(smem + kSideOffF2))[(row - 80) * 11 + (c - 256)] = v;
        }
    }
    __syncthreads();

    const int w  = tid >> 6;
    const int ln = tid & 63;
    const int lr = ln & 15;
    const int lg = ln >> 4;
    const float* sideU = (const float*)(smem + kSideOffU2);
    const float* sideF = (const float*)(smem + kSideOffF2);
    float* xch = (float*)(smem + kXchOff) + w * 320 + lr * 20;

    const int tix  = blockIdx.x;               // 512 tiles of 256 px
    const int b    = tix >> 6;
    const int hw0  = (tix & 63) * 256;
    const int col0 = hw0 + w * 64 + lr;
    const float* bbaseH = h_fea + b * kCH * kHW + lg * 8 * kHW + col0;
    const float* bbaseF = f_fea + b * kCH * kHW + lg * 8 * kHW + col0;

    f32x4 acc[5][4];
    #pragma unroll
    for (int m = 0; m < 5; ++m)
        #pragma unroll
        for (int c = 0; c < 4; ++c) {
            acc[m][c][0] = 0.f; acc[m][c][1] = 0.f;
            acc[m][c][2] = 0.f; acc[m][c][3] = 0.f;
        }
    f32x4 accF[3][4];
    #pragma unroll
    for (int m = 0; m < 3; ++m)
        #pragma unroll
        for (int c = 0; c < 4; ++c) {
            accF[m][c][0] = 0.f; accF[m][c][1] = 0.f;
            accF[m][c][2] = 0.f; accF[m][c][3] = 0.f;
        }

    float nf[4][8];
    bf16x8 bc[4];

    // ---- GEMM 1: uplow vs h_fea ----
    LOADF(bbaseH, 0)
    CVT4()
    LOADF(bbaseH, 1)
    #pragma unroll
    for (int ks = 0; ks < 8; ++ks) {
        const int kb = (ks * 32 + lg * 8) * 2;
        #pragma unroll
        for (int m = 0; m < 5; ++m) {
            const int row = m * 16 + lr;
            const bf16x8 a = *(const bf16x8*)(
                smem + row * 512 + (kb ^ ((row & 7) << 4)));
            #pragma unroll
            for (int c = 0; c < 4; ++c)
                acc[m][c] = __builtin_amdgcn_mfma_f32_16x16x32_bf16(a, bc[c], acc[m][c], 0, 0, 0);
        }
        if (ks < 7) {
            CVT4()
            if (ks < 6) LOADF(bbaseH, ks + 2)
        }
    }

    // ---- GEMM 2: full vs f_fea (rows 80..127) ----
    LOADF(bbaseF, 0)
    CVT4()
    LOADF(bbaseF, 1)
    #pragma unroll
    for (int ks = 0; ks < 8; ++ks) {
        const int kb = (ks * 32 + lg * 8) * 2;
        #pragma unroll
        for (int m = 0; m < 3; ++m) {
            const int row = 80 + m * 16 + lr;
            const bf16x8 a = *(const bf16x8*)(
                smem + row * 512 + (kb ^ ((row & 7) << 4)));
            #pragma unroll
            for (int c = 0; c < 4; ++c)
                accF[m][c] = __builtin_amdgcn_mfma_f32_16x16x32_bf16(a, bc[c], accF[m][c], 0, 0, 0);
        }
        if (ks < 7) {
            CVT4()
            if (ks < 6) LOADF(bbaseF, ks + 2)
        }
    }

    // ---- stage children h into freed A-row LDS region (per-wave, async) ----
    __syncthreads();   // everyone done reading A-rows
    float sU4[4], sL4[4], sF4[4];
    {
        char* stBase = smem + w * 15360;   // 60 rows x 256 B per wave
        #pragma unroll
        for (int n = 0; n < 6; ++n) {
            #pragma unroll
            for (int j = 0; j < 10; ++j) {
                const float* g = out + ((n * kB + b) * kHID + j) * kHW + hw0 + w * 64 + ln;
                __builtin_amdgcn_global_load_lds(
                    (const __attribute__((address_space(1))) unsigned*)g,
                    (__attribute__((address_space(3))) unsigned*)(stBase + (n * 10 + j) * 256),
                    4, 0, 0);
            }
        }
        // seg prefetch rides the stage's latency shadow (independent VMEM loads)
        #pragma unroll
        for (int ct = 0; ct < 4; ++ct) {
            const int px = col0 + ct * 16;
            sU4[ct] = seg_h[(b * 3 + 1) * kHW + px];
            sL4[ct] = seg_h[(b * 3 + 2) * kHW + px];
            sF4[ct] = seg_f[(b * 2 + 1) * kHW + px];
        }
        asm volatile("s_waitcnt vmcnt(0)" ::: "memory");
        __builtin_amdgcn_sched_barrier(0);
    }
    const float* stW = (const float*)(smem + w * 15360);   // [60][64] fp32

    // ---- unified epilogue ----
    #pragma unroll
    for (int ct = 0; ct < 4; ++ct) {
        const int px = col0 + ct * 16;
        const int ix = lr + ct * 16;       // this lane's px within the wave's 64

        const float sU = sU4[ct];
        const float sL = sL4[ct];
        const float sF = sF4[ct];

        float hsU[10], hsL[10];
        #pragma unroll
        for (int j = 0; j < 10; ++j) {
            hsU[j] = stW[(0 * 10 + j) * 64 + ix] + stW[(1 * 10 + j) * 64 + ix]
                   + stW[(2 * 10 + j) * 64 + ix] + stW[(3 * 10 + j) * 64 + ix];
            hsL[j] = stW[(4 * 10 + j) * 64 + ix] + stW[(5 * 10 + j) * 64 + ix];
        }

        float ucv[3] = {0.f, 0.f, 0.f};

        #pragma unroll
        for (int m = 0; m < 5; ++m) {
            const int t = m * 4 + lg;
            if (t < 10) {
                float ai = acc[m][ct][0] + sideU[(t * 4 + 0) * 11] * sU;
                float ag = acc[m][ct][1] + sideU[(t * 4 + 1) * 11] * sU;
                const float pf = acc[m][ct][2] + sideU[(t * 4 + 2) * 11] * sU;
                float cs = 0.f;
                #pragma unroll
                for (int n = 0; n < 4; ++n) {
                    float fh = pf;
                    #pragma unroll
                    for (int j = 0; j < 10; ++j)
                        fh = fmaf(sideU[(t * 4 + 2) * 11 + 1 + j],
                                  stW[(n * 10 + j) * 64 + ix], fh);
                    const float cv = out[(((9 + n) * kB + b) * kHID + t) * kHW + px];
                    cs = fmaf(sigm(fh), cv, cs);
                }
                #pragma unroll
                for (int j = 0; j < 10; ++j) {
                    ai = fmaf(sideU[(t * 4 + 0) * 11 + 1 + j], hsU[j], ai);
                    ag = fmaf(sideU[(t * 4 + 1) * 11 + 1 + j], hsU[j], ag);
                }
                const float uc = sigm(ai) * tanh_(ag) + cs;
                out[((15 * kB + b) * kHID + t) * kHW + px] = uc;
                if (m < 3) ucv[m] = uc;
            } else {
                const int q = t - 10;
                float ai = acc[m][ct][0] + sideU[(t * 4 + 0) * 11] * sL;
                float ag = acc[m][ct][1] + sideU[(t * 4 + 1) * 11] * sL;
                float ao = acc[m][ct][2] + sideU[(t * 4 + 2) * 11] * sL;
                const float pf = acc[m][ct][3] + sideU[(t * 4 + 3) * 11] * sL;
                float cs = 0.f;
                #pragma unroll
                for (int n = 4; n < 6; ++n) {
                    float fh = pf;
                    #pragma unroll
                    for (int j = 0; j < 10; ++j)
                        fh = fmaf(sideU[(t * 4 + 3) * 11 + 1 + j],
                                  stW[(n * 10 + j) * 64 + ix], fh);
                    const float cv = out[(((9 + n) * kB + b) * kHID + q) * kHW + px];
                    cs = fmaf(sigm(fh), cv, cs);
                }
                #pragma unroll
                for (int j = 0; j < 10; ++j) {
                    ai = fmaf(sideU[(t * 4 + 0) * 11 + 1 + j], hsL[j], ai);
                    ag = fmaf(sideU[(t * 4 + 1) * 11 + 1 + j], hsL[j], ag);
                    ao = fmaf(sideU[(t * 4 + 2) * 11 + 1 + j], hsL[j], ao);
                }
                const float lcv = sigm(ai) * tanh_(ag) + cs;
                const float lhv = sigm(ao) * tanh_(lcv);
                out[((6 * kB + b) * kHID + q) * kHW + px]  = lhv;
                out[((7 * kB + b) * kHID + q) * kHW + px]  = lhv;
                out[((16 * kB + b) * kHID + q) * kHW + px] = lcv;
                xch[q]      = lhv;
                xch[10 + q] = lcv;
            }
        }

        asm volatile("s_waitcnt lgkmcnt(0)" ::: "memory");
        __builtin_amdgcn_sched_barrier(0);

        float lhx[10];
        #pragma unroll
        for (int j = 0; j < 10; ++j) lhx[j] = xch[j];

        #pragma unroll
        for (int mf = 0; mf < 3; ++mf) {
            const int t = mf * 4 + lg;
            if (t < 10) {
                float ai = accF[mf][ct][0] + sideF[(t * 4 + 0) * 11] * sF;
                float ag = accF[mf][ct][1] + sideF[(t * 4 + 1) * 11] * sF;
                float ao = accF[mf][ct][2] + sideF[(t * 4 + 2) * 11] * sF;
                float fh = accF[mf][ct][3] + sideF[(t * 4 + 3) * 11] * sF;
                #pragma unroll
                for (int j = 0; j < 10; ++j) {
                    ai = fmaf(sideF[(t * 4 + 0) * 11 + 1 + j], lhx[j], ai);
                    ag = fmaf(sideF[(t * 4 + 1) * 11 + 1 + j], lhx[j], ag);
                    ao = fmaf(sideF[(t * 4 + 2) * 11 + 1 + j], lhx[j], ao);
                    fh = fmaf(sideF[(t * 4 + 3) * 11 + 1 + j], lhx[j], fh);
                }
                const float lcx = xch[10 + t];
                const float cf = sigm(ai) * tanh_(ag) + sigm(fh) * (ucv[mf] + lcx);
                const float hv = sigm(ao) * tanh_(cf);
                out[((8 * kB + b) * kHID + t) * kHW + px]  = hv;
                out[((17 * kB + b) * kHID + t) * kHW + px] = cf;
            }
        }
    }
}

}  // namespace

extern "C" void kernel_launch(void* const* d_in, const int* in_sizes, int n_in,
                              void* d_out, int out_size, void* d_ws, size_t ws_size,
                              hipStream_t stream) {
    const float* seg_p   = (const float*)d_in[0];
    const float* seg_h   = (const float*)d_in[1];
    const float* seg_f   = (const float*)d_in[2];
    const float* p_fea   = (const float*)d_in[3];
    const float* h_fea   = (const float*)d_in[4];
    const float* f_fea   = (const float*)d_in[5];
    const float* W_leaf  = (const float*)d_in[6];
    const float* W_up    = (const float*)d_in[7];
    const float* Wf_up   = (const float*)d_in[8];
    const float* W_low   = (const float*)d_in[9];
    const float* Wf_low  = (const float*)d_in[10];
    const float* W_full  = (const float*)d_in[11];
    const float* Wf_full = (const float*)d_in[12];
    float* out = (float*)d_out;

    // fused kernel uses >64 KB dynamic LDS
    (void)hipFuncSetAttribute(reinterpret_cast<const void*>(k_uplow_full_mfma),
                              hipFuncAttributeMaxDynamicSharedMemorySize, kLdsBytesUF);

    hipLaunchKernelGGL(k_leaf_mfma, dim3(768), dim3(256), kLdsBytesL, stream,
                       p_fea, seg_p, W_leaf, out);
    hipLaunchKernelGGL(k_uplow_full_mfma, dim3(512), dim3(256), kLdsBytesUF, stream,
                       h_fea, f_fea, seg_h, seg_f,
                       W_up, Wf_up, W_low, Wf_low, W_full, Wf_full, out);
}

// Round 18
// 247.256 us; speedup vs baseline: 1.2079x; 1.0047x over previous
//
#include <hip/hip_runtime.h>

namespace {

constexpr int kHW  = 128 * 128;
constexpr int kCH  = 256;
constexpr int kHID = 10;
constexpr int kB   = 8;

typedef __attribute__((ext_vector_type(8))) short bf16x8;
typedef __attribute__((ext_vector_type(4))) float f32x4;

// leaf (per 2-leaf class): 80 rows bf16 + seg table 20 quads x 4 fp32
constexpr int kSegOffL   = 80 * 512;
constexpr int kLdsBytesL = kSegOffL + 20 * 4 * 4;

// fused uplow+full: 128 A-rows + sideU [80][11] + sideF [48][11] + xch [8][16][20]
// After GEMM2 the A-row region [0, 61440) is reused as children-h stage:
//   4 waves x 60 rows x 256 B = 61440 B (h[n][j][px] per wave's 64 px)
constexpr int kSideOffU2 = 128 * 512;                    // 65536
constexpr int kSideOffF2 = kSideOffU2 + 80 * 11 * 4;     // 69056
constexpr int kXchOff    = kSideOffF2 + 48 * 11 * 4;     // 71168
constexpr int kLdsBytesUF = kXchOff + 8 * 16 * 20 * 4;   // 81408

__device__ __forceinline__ float sigm(float x) {
    return __builtin_amdgcn_rcpf(1.0f + __expf(-x));
}
__device__ __forceinline__ float tanh_(float x) {
    return 1.0f - 2.0f * __builtin_amdgcn_rcpf(__expf(2.0f * x) + 1.0f);
}
__device__ __forceinline__ unsigned short bf16b(float f) {
    unsigned u = __float_as_uint(f);
    return (unsigned short)((u + 0x7FFFu + ((u >> 16) & 1u)) >> 16);  // RNE (staging only)
}
// 8 fp32 -> bf16x8 via 4x v_cvt_pk_bf16_f32 (RNE)
__device__ __forceinline__ bf16x8 cvt8(const float* v) {
    union { unsigned u[4]; bf16x8 h; } r;
    #pragma unroll
    for (int i = 0; i < 4; ++i)
        asm("v_cvt_pk_bf16_f32 %0, %1, %2"
            : "=v"(r.u[i]) : "v"(v[2 * i]), "v"(v[2 * i + 1]));
    return r.h;
}

// issue 4 cols x 8 channels of strided fp32 loads for K-step `step` from `base`
#define LOADF(base, step)                                                  \
    { const float* p_ = (base) + (step) * 32 * kHW;                        \
      _Pragma("unroll") for (int c_ = 0; c_ < 4; ++c_)                     \
      _Pragma("unroll") for (int j_ = 0; j_ < 8; ++j_)                     \
          nf[c_][j_] = p_[c_ * 16 + j_ * kHW]; }

#define CVT4()                                                             \
    { _Pragma("unroll") for (int c_ = 0; c_ < 4; ++c_) bc[c_] = cvt8(nf[c_]); }

// ---------------- Kernel 1 (MFMA): leaf cells (2 tiles/block, in-epilogue seg) ----------------
// 20 triples t, rows t*4+{0:i,1:g,2:o,3:pad}; 5 M-tiles.
// Block = (cls, pair); handles tiles pair and pair+256 with ONE weight stage.
// bid = pairGroup*24 + cls*8 + pairLow: same-pair cls-blocks differ by 8 -> same XCD.
// R18: seg loads back in the epilogue (R16's segv[5][4] hoist may have pushed the
// register total past the 3-waves/SIMD boundary; R16 was neutral = gain canceled).
__global__ __launch_bounds__(256, 3) void k_leaf_mfma(
    const float* __restrict__ p_fea,   // [B, CH, HW]
    const float* __restrict__ seg_p,   // [B, 7, HW]
    const float* __restrict__ W_leaf,  // [6, 30, 257]
    float* __restrict__ out)           // [18, B, 10, HW]
{
    extern __shared__ char smem[];
    const int tid   = threadIdx.x;
    const int bid   = blockIdx.x;              // 768 = 3 cls x 256 pairs
    const int group = bid / 24;                // pair/8
    const int rem   = bid - group * 24;
    const int cls   = rem >> 3;                // 0..2
    const int pair  = group * 8 + (rem & 7);   // 0..255

    for (int idx = tid; idx < 2 * 30 * 257; idx += 256) {
        const int np   = idx / 7710;
        const int rrem = idx - np * 7710;
        const int orow = rrem / 257;
        const int c    = rrem - orow * 257;
        const int g    = orow / 10;            // 0=i,1=o,2=g (reference order)
        const int q    = orow - g * 10;
        const int slot = (g == 0) ? 0 : (g == 1 ? 2 : 1);   // (i,g,o,pad)
        const int t    = np * 10 + q;
        const float v  = W_leaf[(cls * 2 + np) * 7710 + rrem];
        if (c == 256) {
            ((float*)(smem + kSegOffL))[t * 4 + slot] = v;
        } else {
            const int row  = t * 4 + slot;
            const int byte = row * 512 + ((2 * c) ^ ((row & 7) << 4));
            *(unsigned short*)(smem + byte) = bf16b(v);
        }
    }
    for (int i = tid; i < 20 * 128; i += 256) {   // zero pad rows (slot 3)
        const int t = i >> 7, d = i & 127;
        *(unsigned*)(smem + (t * 4 + 3) * 512 + d * 4) = 0u;
    }
    if (tid < 20) ((float*)(smem + kSegOffL))[tid * 4 + 3] = 0.f;
    __syncthreads();

    const int w  = tid >> 6;
    const int ln = tid & 63;
    const int lr = ln & 15;
    const int lg = ln >> 4;

    #pragma unroll 1
    for (int tp = 0; tp < 2; ++tp) {
        const int tile = pair + tp * 256;       // 0..511
        const int b    = tile >> 6;
        const int hw0  = (tile & 63) * 256;
        const int col0 = hw0 + w * 64 + lr;
        const float* bbase = p_fea + b * kCH * kHW + lg * 8 * kHW + col0;

        f32x4 acc[5][4];
        #pragma unroll
        for (int m = 0; m < 5; ++m)
            #pragma unroll
            for (int c = 0; c < 4; ++c) {
                acc[m][c][0] = 0.f; acc[m][c][1] = 0.f;
                acc[m][c][2] = 0.f; acc[m][c][3] = 0.f;
            }

        float nf[4][8];
        bf16x8 bc[4];
        LOADF(bbase, 0)
        CVT4()
        LOADF(bbase, 1)

        #pragma unroll
        for (int ks = 0; ks < 8; ++ks) {
            const int kb = (ks * 32 + lg * 8) * 2;
            #pragma unroll
            for (int m = 0; m < 5; ++m) {
                const int row = m * 16 + lr;
                const bf16x8 a = *(const bf16x8*)(
                    smem + row * 512 + (kb ^ ((row & 7) << 4)));
                #pragma unroll
                for (int c = 0; c < 4; ++c)
                    acc[m][c] = __builtin_amdgcn_mfma_f32_16x16x32_bf16(a, bc[c], acc[m][c], 0, 0, 0);
            }
            if (ks < 7) {
                CVT4()
                if (ks < 6) LOADF(bbase, ks + 2)
            }
        }

        #pragma unroll
        for (int m = 0; m < 5; ++m) {
            const int t = m * 4 + lg;                   // local triple < 20
            const int n = cls * 2 + t / 10;             // global leaf
            const int q = t % 10;
            const float4 sw = *(const float4*)(smem + kSegOffL + t * 16);
            const float* sp = seg_p + (b * 7 + n + 1) * kHW;
            float* oh = out + ((n * kB + b) * kHID + q) * kHW;
            float* oc = out + (((9 + n) * kB + b) * kHID + q) * kHW;
            #pragma unroll
            for (int ct = 0; ct < 4; ++ct) {
                const int px = col0 + ct * 16;
                const float sg = sp[px];
                const float ci = acc[m][ct][0] + sw.x * sg;
                const float cg = acc[m][ct][1] + sw.y * sg;
                const float co = acc[m][ct][2] + sw.z * sg;
                const float c  = sigm(ci) * tanh_(cg);
                const float h  = sigm(co) * tanh_(c);
                oh[px] = h;
                oc[px] = c;
            }
        }
    }
}

// ---------------- Kernel 2 (MFMA): fused up + low + full tree cells (R17 verbatim) ----------------
// A-rows 0..79: uplow quads (up t=0..9: {i,g,f,pad}; low t=10..19: {i,g,o,f})
// A-rows 80..127: full quads t=0..9: {i,g,o,f}; t=10,11 pad.
// full's h-coupling (h_sum = 2*low_h) folded x2 into sideF for i,g,o (not f).
// Epilogue: children h staged via global_load_lds into freed A-row region;
// the 12 seg loads ride the same vmcnt shadow.
__global__ __launch_bounds__(256, 2) void k_uplow_full_mfma(
    const float* __restrict__ h_fea,   // [B, CH, HW]
    const float* __restrict__ f_fea,   // [B, CH, HW]
    const float* __restrict__ seg_h,   // [B, 3, HW]
    const float* __restrict__ seg_f,   // [B, 2, HW]
    const float* __restrict__ W_up,    const float* __restrict__ Wf_up,
    const float* __restrict__ W_low,   const float* __restrict__ Wf_low,
    const float* __restrict__ W_full,  const float* __restrict__ Wf_full,
    float* __restrict__ out)
{
    extern __shared__ char smem[];
    const int tid = threadIdx.x;

    for (int idx = tid; idx < 128 * 267; idx += 256) {
        const int row = idx / 267;
        const int c   = idx - row * 267;
        float v = 0.f;
        if (row < 80) {
            const int t = row >> 2, slot = row & 3;
            if (t < 10) {
                if      (slot == 0) v = W_up[t * 267 + c];
                else if (slot == 1) v = W_up[(20 + t) * 267 + c];
                else if (slot == 2) v = Wf_up[t * 267 + c];
            } else {
                const int q = t - 10;
                if      (slot == 0) v = W_low[q * 267 + c];
                else if (slot == 1) v = W_low[(20 + q) * 267 + c];
                else if (slot == 2) v = W_low[(10 + q) * 267 + c];
                else                v = Wf_low[q * 267 + c];
            }
        } else {
            const int r2 = row - 80;
            const int t = r2 >> 2, slot = r2 & 3;
            if (t < 10) {
                if      (slot == 0) v = W_full[t * 267 + c];
                else if (slot == 1) v = W_full[(20 + t) * 267 + c];
                else if (slot == 2) v = W_full[(10 + t) * 267 + c];
                else                v = Wf_full[t * 267 + c];
                if (c >= 257 && slot < 3) v *= 2.0f;   // h_sum = 2*low_h
            }
        }
        if (c < 256) {
            const int byte = row * 512 + ((2 * c) ^ ((row & 7) << 4));
            *(unsigned short*)(smem + byte) = bf16b(v);
        } else if (row < 80) {
            ((float*)(smem + kSideOffU2))[row * 11 + (c - 256)] = v;
        } else {
            ((float*)(smem + kSideOffF2))[(row - 80) * 11 + (c - 256)] = v;
        }
    }
    __syncthreads();

    const int w  = tid >> 6;
    const int ln = tid & 63;
    const int lr = ln & 15;
    const int lg = ln >> 4;
    const float* sideU = (const float*)(smem + kSideOffU2);
    const float* sideF = (const float*)(smem + kSideOffF2);
    float* xch = (float*)(smem + kXchOff) + w * 320 + lr * 20;

    const int tix  = blockIdx.x;               // 512 tiles of 256 px
    const int b    = tix >> 6;
    const int hw0  = (tix & 63) * 256;
    const int col0 = hw0 + w * 64 + lr;
    const float* bbaseH = h_fea + b * kCH * kHW + lg * 8 * kHW + col0;
    const float* bbaseF = f_fea + b * kCH * kHW + lg * 8 * kHW + col0;

    f32x4 acc[5][4];
    #pragma unroll
    for (int m = 0; m < 5; ++m)
        #pragma unroll
        for (int c = 0; c < 4; ++c) {
            acc[m][c][0] = 0.f; acc[m][c][1] = 0.f;
            acc[m][c][2] = 0.f; acc[m][c][3] = 0.f;
        }
    f32x4 accF[3][4];
    #pragma unroll
    for (int m = 0; m < 3; ++m)
        #pragma unroll
        for (int c = 0; c < 4; ++c) {
            accF[m][c][0] = 0.f; accF[m][c][1] = 0.f;
            accF[m][c][2] = 0.f; accF[m][c][3] = 0.f;
        }

    float nf[4][8];
    bf16x8 bc[4];

    // ---- GEMM 1: uplow vs h_fea ----
    LOADF(bbaseH, 0)
    CVT4()
    LOADF(bbaseH, 1)
    #pragma unroll
    for (int ks = 0; ks < 8; ++ks) {
        const int kb = (ks * 32 + lg * 8) * 2;
        #pragma unroll
        for (int m = 0; m < 5; ++m) {
            const int row = m * 16 + lr;
            const bf16x8 a = *(const bf16x8*)(
                smem + row * 512 + (kb ^ ((row & 7) << 4)));
            #pragma unroll
            for (int c = 0; c < 4; ++c)
                acc[m][c] = __builtin_amdgcn_mfma_f32_16x16x32_bf16(a, bc[c], acc[m][c], 0, 0, 0);
        }
        if (ks < 7) {
            CVT4()
            if (ks < 6) LOADF(bbaseH, ks + 2)
        }
    }

    // ---- GEMM 2: full vs f_fea (rows 80..127) ----
    LOADF(bbaseF, 0)
    CVT4()
    LOADF(bbaseF, 1)
    #pragma unroll
    for (int ks = 0; ks < 8; ++ks) {
        const int kb = (ks * 32 + lg * 8) * 2;
        #pragma unroll
        for (int m = 0; m < 3; ++m) {
            const int row = 80 + m * 16 + lr;
            const bf16x8 a = *(const bf16x8*)(
                smem + row * 512 + (kb ^ ((row & 7) << 4)));
            #pragma unroll
            for (int c = 0; c < 4; ++c)
                accF[m][c] = __builtin_amdgcn_mfma_f32_16x16x32_bf16(a, bc[c], accF[m][c], 0, 0, 0);
        }
        if (ks < 7) {
            CVT4()
            if (ks < 6) LOADF(bbaseF, ks + 2)
        }
    }

    // ---- stage children h into freed A-row LDS region (per-wave, async) ----
    __syncthreads();   // everyone done reading A-rows
    float sU4[4], sL4[4], sF4[4];
    {
        char* stBase = smem + w * 15360;   // 60 rows x 256 B per wave
        #pragma unroll
        for (int n = 0; n < 6; ++n) {
            #pragma unroll
            for (int j = 0; j < 10; ++j) {
                const float* g = out + ((n * kB + b) * kHID + j) * kHW + hw0 + w * 64 + ln;
                __builtin_amdgcn_global_load_lds(
                    (const __attribute__((address_space(1))) unsigned*)g,
                    (__attribute__((address_space(3))) unsigned*)(stBase + (n * 10 + j) * 256),
                    4, 0, 0);
            }
        }
        // seg prefetch rides the stage's latency shadow (independent VMEM loads)
        #pragma unroll
        for (int ct = 0; ct < 4; ++ct) {
            const int px = col0 + ct * 16;
            sU4[ct] = seg_h[(b * 3 + 1) * kHW + px];
            sL4[ct] = seg_h[(b * 3 + 2) * kHW + px];
            sF4[ct] = seg_f[(b * 2 + 1) * kHW + px];
        }
        asm volatile("s_waitcnt vmcnt(0)" ::: "memory");
        __builtin_amdgcn_sched_barrier(0);
    }
    const float* stW = (const float*)(smem + w * 15360);   // [60][64] fp32

    // ---- unified epilogue ----
    #pragma unroll
    for (int ct = 0; ct < 4; ++ct) {
        const int px = col0 + ct * 16;
        const int ix = lr + ct * 16;       // this lane's px within the wave's 64

        const float sU = sU4[ct];
        const float sL = sL4[ct];
        const float sF = sF4[ct];

        float hsU[10], hsL[10];
        #pragma unroll
        for (int j = 0; j < 10; ++j) {
            hsU[j] = stW[(0 * 10 + j) * 64 + ix] + stW[(1 * 10 + j) * 64 + ix]
                   + stW[(2 * 10 + j) * 64 + ix] + stW[(3 * 10 + j) * 64 + ix];
            hsL[j] = stW[(4 * 10 + j) * 64 + ix] + stW[(5 * 10 + j) * 64 + ix];
        }

        float ucv[3] = {0.f, 0.f, 0.f};

        #pragma unroll
        for (int m = 0; m < 5; ++m) {
            const int t = m * 4 + lg;
            if (t < 10) {
                float ai = acc[m][ct][0] + sideU[(t * 4 + 0) * 11] * sU;
                float ag = acc[m][ct][1] + sideU[(t * 4 + 1) * 11] * sU;
                const float pf = acc[m][ct][2] + sideU[(t * 4 + 2) * 11] * sU;
                float cs = 0.f;
                #pragma unroll
                for (int n = 0; n < 4; ++n) {
                    float fh = pf;
                    #pragma unroll
                    for (int j = 0; j < 10; ++j)
                        fh = fmaf(sideU[(t * 4 + 2) * 11 + 1 + j],
                                  stW[(n * 10 + j) * 64 + ix], fh);
                    const float cv = out[(((9 + n) * kB + b) * kHID + t) * kHW + px];
                    cs = fmaf(sigm(fh), cv, cs);
                }
                #pragma unroll
                for (int j = 0; j < 10; ++j) {
                    ai = fmaf(sideU[(t * 4 + 0) * 11 + 1 + j], hsU[j], ai);
                    ag = fmaf(sideU[(t * 4 + 1) * 11 + 1 + j], hsU[j], ag);
                }
                const float uc = sigm(ai) * tanh_(ag) + cs;
                out[((15 * kB + b) * kHID + t) * kHW + px] = uc;
                if (m < 3) ucv[m] = uc;
            } else {
                const int q = t - 10;
                float ai = acc[m][ct][0] + sideU[(t * 4 + 0) * 11] * sL;
                float ag = acc[m][ct][1] + sideU[(t * 4 + 1) * 11] * sL;
                float ao = acc[m][ct][2] + sideU[(t * 4 + 2) * 11] * sL;
                const float pf = acc[m][ct][3] + sideU[(t * 4 + 3) * 11] * sL;
                float cs = 0.f;
                #pragma unroll
                for (int n = 4; n < 6; ++n) {
                    float fh = pf;
                    #pragma unroll
                    for (int j = 0; j < 10; ++j)
                        fh = fmaf(sideU[(t * 4 + 3) * 11 + 1 + j],
                                  stW[(n * 10 + j) * 64 + ix], fh);
                    const float cv = out[(((9 + n) * kB + b) * kHID + q) * kHW + px];
                    cs = fmaf(sigm(fh), cv, cs);
                }
                #pragma unroll
                for (int j = 0; j < 10; ++j) {
                    ai = fmaf(sideU[(t * 4 + 0) * 11 + 1 + j], hsL[j], ai);
                    ag = fmaf(sideU[(t * 4 + 1) * 11 + 1 + j], hsL[j], ag);
                    ao = fmaf(sideU[(t * 4 + 2) * 11 + 1 + j], hsL[j], ao);
                }
                const float lcv = sigm(ai) * tanh_(ag) + cs;
                const float lhv = sigm(ao) * tanh_(lcv);
                out[((6 * kB + b) * kHID + q) * kHW + px]  = lhv;
                out[((7 * kB + b) * kHID + q) * kHW + px]  = lhv;
                out[((16 * kB + b) * kHID + q) * kHW + px] = lcv;
                xch[q]      = lhv;
                xch[10 + q] = lcv;
            }
        }

        asm volatile("s_waitcnt lgkmcnt(0)" ::: "memory");
        __builtin_amdgcn_sched_barrier(0);

        float lhx[10];
        #pragma unroll
        for (int j = 0; j < 10; ++j) lhx[j] = xch[j];

        #pragma unroll
        for (int mf = 0; mf < 3; ++mf) {
            const int t = mf * 4 + lg;
            if (t < 10) {
                float ai = accF[mf][ct][0] + sideF[(t * 4 + 0) * 11] * sF;
                float ag = accF[mf][ct][1] + sideF[(t * 4 + 1) * 11] * sF;
                float ao = accF[mf][ct][2] + sideF[(t * 4 + 2) * 11] * sF;
                float fh = accF[mf][ct][3] + sideF[(t * 4 + 3) * 11] * sF;
                #pragma unroll
                for (int j = 0; j < 10; ++j) {
                    ai = fmaf(sideF[(t * 4 + 0) * 11 + 1 + j], lhx[j], ai);
                    ag = fmaf(sideF[(t * 4 + 1) * 11 + 1 + j], lhx[j], ag);
                    ao = fmaf(sideF[(t * 4 + 2) * 11 + 1 + j], lhx[j], ao);
                    fh = fmaf(sideF[(t * 4 + 3) * 11 + 1 + j], lhx[j], fh);
                }
                const float lcx = xch[10 + t];
                const float cf = sigm(ai) * tanh_(ag) + sigm(fh) * (ucv[mf] + lcx);
                const float hv = sigm(ao) * tanh_(cf);
                out[((8 * kB + b) * kHID + t) * kHW + px]  = hv;
                out[((17 * kB + b) * kHID + t) * kHW + px] = cf;
            }
        }
    }
}

}  // namespace

extern "C" void kernel_launch(void* const* d_in, const int* in_sizes, int n_in,
                              void* d_out, int out_size, void* d_ws, size_t ws_size,
                              hipStream_t stream) {
    const float* seg_p   = (const float*)d_in[0];
    const float* seg_h   = (const float*)d_in[1];
    const float* seg_f   = (const float*)d_in[2];
    const float* p_fea   = (const float*)d_in[3];
    const float* h_fea   = (const float*)d_in[4];
    const float* f_fea   = (const float*)d_in[5];
    const float* W_leaf  = (const float*)d_in[6];
    const float* W_up    = (const float*)d_in[7];
    const float* Wf_up   = (const float*)d_in[8];
    const float* W_low   = (const float*)d_in[9];
    const float* Wf_low  = (const float*)d_in[10];
    const float* W_full  = (const float*)d_in[11];
    const float* Wf_full = (const float*)d_in[12];
    float* out = (float*)d_out;

    // fused kernel uses >64 KB dynamic LDS
    (void)hipFuncSetAttribute(reinterpret_cast<const void*>(k_uplow_full_mfma),
                              hipFuncAttributeMaxDynamicSharedMemorySize, kLdsBytesUF);

    hipLaunchKernelGGL(k_leaf_mfma, dim3(768), dim3(256), kLdsBytesL, stream,
                       p_fea, seg_p, W_leaf, out);
    hipLaunchKernelGGL(k_uplow_full_mfma, dim3(512), dim3(256), kLdsBytesUF, stream,
                       h_fea, f_fea, seg_h, seg_f,
                       W_up, Wf_up, W_low, Wf_low, W_full, Wf_full, out);
}

// Round 19
// 245.234 us; speedup vs baseline: 1.2179x; 1.0082x over previous
//
#include <hip/hip_runtime.h>

namespace {

constexpr int kHW  = 128 * 128;
constexpr int kCH  = 256;
constexpr int kHID = 10;
constexpr int kB   = 8;

typedef __attribute__((ext_vector_type(8))) short bf16x8;
typedef __attribute__((ext_vector_type(4))) float f32x4;

// leaf (per 2-leaf class): 80 rows bf16 + seg table 20 quads x 4 fp32
constexpr int kSegOffL   = 80 * 512;
constexpr int kLdsBytesL = kSegOffL + 20 * 4 * 4;

// fused uplow+full: 128 A-rows + sideU [80][11] + sideF [48][11] + xch [8][16][20]
// After GEMM2 the A-row region [0, 61440) is reused as children-h stage:
//   4 waves x 60 rows x 256 B = 61440 B (h[n][j][px] per wave's 64 px)
constexpr int kSideOffU2 = 128 * 512;                    // 65536
constexpr int kSideOffF2 = kSideOffU2 + 80 * 11 * 4;     // 69056
constexpr int kXchOff    = kSideOffF2 + 48 * 11 * 4;     // 71168
constexpr int kLdsBytesUF = kXchOff + 8 * 16 * 20 * 4;   // 81408

__device__ __forceinline__ float sigm(float x) {
    return __builtin_amdgcn_rcpf(1.0f + __expf(-x));
}
__device__ __forceinline__ float tanh_(float x) {
    return 1.0f - 2.0f * __builtin_amdgcn_rcpf(__expf(2.0f * x) + 1.0f);
}
__device__ __forceinline__ unsigned short bf16b(float f) {
    unsigned u = __float_as_uint(f);
    return (unsigned short)((u + 0x7FFFu + ((u >> 16) & 1u)) >> 16);  // RNE (staging only)
}
// 8 fp32 -> bf16x8 via 4x v_cvt_pk_bf16_f32 (RNE)
__device__ __forceinline__ bf16x8 cvt8(const float* v) {
    union { unsigned u[4]; bf16x8 h; } r;
    #pragma unroll
    for (int i = 0; i < 4; ++i)
        asm("v_cvt_pk_bf16_f32 %0, %1, %2"
            : "=v"(r.u[i]) : "v"(v[2 * i]), "v"(v[2 * i + 1]));
    return r.h;
}

// issue 4 cols x 8 channels of strided fp32 loads for K-step `step` from `base`
#define LOADF(base, step)                                                  \
    { const float* p_ = (base) + (step) * 32 * kHW;                        \
      _Pragma("unroll") for (int c_ = 0; c_ < 4; ++c_)                     \
      _Pragma("unroll") for (int j_ = 0; j_ < 8; ++j_)                     \
          nf[c_][j_] = p_[c_ * 16 + j_ * kHW]; }

#define CVT4()                                                             \
    { _Pragma("unroll") for (int c_ = 0; c_ < 4; ++c_) bc[c_] = cvt8(nf[c_]); }

// ---------------- Kernel 1 (MFMA): leaf cells (2 tiles/block) ----------------
// 20 triples t, rows t*4+{0:i,1:g,2:o,3:pad}; 5 M-tiles.
// Block = (cls, pair); handles tiles pair and pair+256 with ONE weight stage.
// bid = pairGroup*24 + cls*8 + pairLow: same-pair cls-blocks differ by 8 -> same XCD.
// R19: staging loop unrolled x4 so independent global loads pipeline (no serial
// latency chain; loads don't alias the LDS stores).
__global__ __launch_bounds__(256, 3) void k_leaf_mfma(
    const float* __restrict__ p_fea,   // [B, CH, HW]
    const float* __restrict__ seg_p,   // [B, 7, HW]
    const float* __restrict__ W_leaf,  // [6, 30, 257]
    float* __restrict__ out)           // [18, B, 10, HW]
{
    extern __shared__ char smem[];
    const int tid   = threadIdx.x;
    const int bid   = blockIdx.x;              // 768 = 3 cls x 256 pairs
    const int group = bid / 24;                // pair/8
    const int rem   = bid - group * 24;
    const int cls   = rem >> 3;                // 0..2
    const int pair  = group * 8 + (rem & 7);   // 0..255

    #pragma unroll 4
    for (int idx = tid; idx < 2 * 30 * 257; idx += 256) {
        const int np   = idx / 7710;
        const int rrem = idx - np * 7710;
        const int orow = rrem / 257;
        const int c    = rrem - orow * 257;
        const int g    = orow / 10;            // 0=i,1=o,2=g (reference order)
        const int q    = orow - g * 10;
        const int slot = (g == 0) ? 0 : (g == 1 ? 2 : 1);   // (i,g,o,pad)
        const int t    = np * 10 + q;
        const float v  = W_leaf[(cls * 2 + np) * 7710 + rrem];
        if (c == 256) {
            ((float*)(smem + kSegOffL))[t * 4 + slot] = v;
        } else {
            const int row  = t * 4 + slot;
            const int byte = row * 512 + ((2 * c) ^ ((row & 7) << 4));
            *(unsigned short*)(smem + byte) = bf16b(v);
        }
    }
    for (int i = tid; i < 20 * 128; i += 256) {   // zero pad rows (slot 3)
        const int t = i >> 7, d = i & 127;
        *(unsigned*)(smem + (t * 4 + 3) * 512 + d * 4) = 0u;
    }
    if (tid < 20) ((float*)(smem + kSegOffL))[tid * 4 + 3] = 0.f;
    __syncthreads();

    const int w  = tid >> 6;
    const int ln = tid & 63;
    const int lr = ln & 15;
    const int lg = ln >> 4;

    #pragma unroll 1
    for (int tp = 0; tp < 2; ++tp) {
        const int tile = pair + tp * 256;       // 0..511
        const int b    = tile >> 6;
        const int hw0  = (tile & 63) * 256;
        const int col0 = hw0 + w * 64 + lr;
        const float* bbase = p_fea + b * kCH * kHW + lg * 8 * kHW + col0;

        f32x4 acc[5][4];
        #pragma unroll
        for (int m = 0; m < 5; ++m)
            #pragma unroll
            for (int c = 0; c < 4; ++c) {
                acc[m][c][0] = 0.f; acc[m][c][1] = 0.f;
                acc[m][c][2] = 0.f; acc[m][c][3] = 0.f;
            }

        float nf[4][8];
        bf16x8 bc[4];
        LOADF(bbase, 0)
        CVT4()
        LOADF(bbase, 1)

        #pragma unroll
        for (int ks = 0; ks < 8; ++ks) {
            const int kb = (ks * 32 + lg * 8) * 2;
            #pragma unroll
            for (int m = 0; m < 5; ++m) {
                const int row = m * 16 + lr;
                const bf16x8 a = *(const bf16x8*)(
                    smem + row * 512 + (kb ^ ((row & 7) << 4)));
                #pragma unroll
                for (int c = 0; c < 4; ++c)
                    acc[m][c] = __builtin_amdgcn_mfma_f32_16x16x32_bf16(a, bc[c], acc[m][c], 0, 0, 0);
            }
            if (ks < 7) {
                CVT4()
                if (ks < 6) LOADF(bbase, ks + 2)
            }
        }

        #pragma unroll
        for (int m = 0; m < 5; ++m) {
            const int t = m * 4 + lg;                   // local triple < 20
            const int n = cls * 2 + t / 10;             // global leaf
            const int q = t % 10;
            const float4 sw = *(const float4*)(smem + kSegOffL + t * 16);
            const float* sp = seg_p + (b * 7 + n + 1) * kHW;
            float* oh = out + ((n * kB + b) * kHID + q) * kHW;
            float* oc = out + (((9 + n) * kB + b) * kHID + q) * kHW;
            #pragma unroll
            for (int ct = 0; ct < 4; ++ct) {
                const int px = col0 + ct * 16;
                const float sg = sp[px];
                const float ci = acc[m][ct][0] + sw.x * sg;
                const float cg = acc[m][ct][1] + sw.y * sg;
                const float co = acc[m][ct][2] + sw.z * sg;
                const float c  = sigm(ci) * tanh_(cg);
                const float h  = sigm(co) * tanh_(c);
                oh[px] = h;
                oc[px] = c;
            }
        }
    }
}

// ---------------- Kernel 2 (MFMA): fused up + low + full tree cells ----------------
// A-rows 0..79: uplow quads (up t=0..9: {i,g,f,pad}; low t=10..19: {i,g,o,f})
// A-rows 80..127: full quads t=0..9: {i,g,o,f}; t=10,11 pad.
// full's h-coupling (h_sum = 2*low_h) folded x2 into sideF for i,g,o (not f).
// Epilogue: children h staged via global_load_lds into freed A-row region;
// the 12 seg loads ride the same vmcnt shadow.
// R19: staging loop unrolled x8 (134 independent iterations -> pipelined loads).
__global__ __launch_bounds__(256, 2) void k_uplow_full_mfma(
    const float* __restrict__ h_fea,   // [B, CH, HW]
    const float* __restrict__ f_fea,   // [B, CH, HW]
    const float* __restrict__ seg_h,   // [B, 3, HW]
    const float* __restrict__ seg_f,   // [B, 2, HW]
    const float* __restrict__ W_up,    const float* __restrict__ Wf_up,
    const float* __restrict__ W_low,   const float* __restrict__ Wf_low,
    const float* __restrict__ W_full,  const float* __restrict__ Wf_full,
    float* __restrict__ out)
{
    extern __shared__ char smem[];
    const int tid = threadIdx.x;

    #pragma unroll 8
    for (int idx = tid; idx < 128 * 267; idx += 256) {
        const int row = idx / 267;
        const int c   = idx - row * 267;
        float v = 0.f;
        if (row < 80) {
            const int t = row >> 2, slot = row & 3;
            if (t < 10) {
                if      (slot == 0) v = W_up[t * 267 + c];
                else if (slot == 1) v = W_up[(20 + t) * 267 + c];
                else if (slot == 2) v = Wf_up[t * 267 + c];
            } else {
                const int q = t - 10;
                if      (slot == 0) v = W_low[q * 267 + c];
                else if (slot == 1) v = W_low[(20 + q) * 267 + c];
                else if (slot == 2) v = W_low[(10 + q) * 267 + c];
                else                v = Wf_low[q * 267 + c];
            }
        } else {
            const int r2 = row - 80;
            const int t = r2 >> 2, slot = r2 & 3;
            if (t < 10) {
                if      (slot == 0) v = W_full[t * 267 + c];
                else if (slot == 1) v = W_full[(20 + t) * 267 + c];
                else if (slot == 2) v = W_full[(10 + t) * 267 + c];
                else                v = Wf_full[t * 267 + c];
                if (c >= 257 && slot < 3) v *= 2.0f;   // h_sum = 2*low_h
            }
        }
        if (c < 256) {
            const int byte = row * 512 + ((2 * c) ^ ((row & 7) << 4));
            *(unsigned short*)(smem + byte) = bf16b(v);
        } else if (row < 80) {
            ((float*)(smem + kSideOffU2))[row * 11 + (c - 256)] = v;
        } else {
            ((float*)(smem + kSideOffF2))[(row - 80) * 11 + (c - 256)] = v;
        }
    }
    __syncthreads();

    const int w  = tid >> 6;
    const int ln = tid & 63;
    const int lr = ln & 15;
    const int lg = ln >> 4;
    const float* sideU = (const float*)(smem + kSideOffU2);
    const float* sideF = (const float*)(smem + kSideOffF2);
    float* xch = (float*)(smem + kXchOff) + w * 320 + lr * 20;

    const int tix  = blockIdx.x;               // 512 tiles of 256 px
    const int b    = tix >> 6;
    const int hw0  = (tix & 63) * 256;
    const int col0 = hw0 + w * 64 + lr;
    const float* bbaseH = h_fea + b * kCH * kHW + lg * 8 * kHW + col0;
    const float* bbaseF = f_fea + b * kCH * kHW + lg * 8 * kHW + col0;

    f32x4 acc[5][4];
    #pragma unroll
    for (int m = 0; m < 5; ++m)
        #pragma unroll
        for (int c = 0; c < 4; ++c) {
            acc[m][c][0] = 0.f; acc[m][c][1] = 0.f;
            acc[m][c][2] = 0.f; acc[m][c][3] = 0.f;
        }
    f32x4 accF[3][4];
    #pragma unroll
    for (int m = 0; m < 3; ++m)
        #pragma unroll
        for (int c = 0; c < 4; ++c) {
            accF[m][c][0] = 0.f; accF[m][c][1] = 0.f;
            accF[m][c][2] = 0.f; accF[m][c][3] = 0.f;
        }

    float nf[4][8];
    bf16x8 bc[4];

    // ---- GEMM 1: uplow vs h_fea ----
    LOADF(bbaseH, 0)
    CVT4()
    LOADF(bbaseH, 1)
    #pragma unroll
    for (int ks = 0; ks < 8; ++ks) {
        const int kb = (ks * 32 + lg * 8) * 2;
        #pragma unroll
        for (int m = 0; m < 5; ++m) {
            const int row = m * 16 + lr;
            const bf16x8 a = *(const bf16x8*)(
                smem + row * 512 + (kb ^ ((row & 7) << 4)));
            #pragma unroll
            for (int c = 0; c < 4; ++c)
                acc[m][c] = __builtin_amdgcn_mfma_f32_16x16x32_bf16(a, bc[c], acc[m][c], 0, 0, 0);
        }
        if (ks < 7) {
            CVT4()
            if (ks < 6) LOADF(bbaseH, ks + 2)
        }
    }

    // ---- GEMM 2: full vs f_fea (rows 80..127) ----
    LOADF(bbaseF, 0)
    CVT4()
    LOADF(bbaseF, 1)
    #pragma unroll
    for (int ks = 0; ks < 8; ++ks) {
        const int kb = (ks * 32 + lg * 8) * 2;
        #pragma unroll
        for (int m = 0; m < 3; ++m) {
            const int row = 80 + m * 16 + lr;
            const bf16x8 a = *(const bf16x8*)(
                smem + row * 512 + (kb ^ ((row & 7) << 4)));
            #pragma unroll
            for (int c = 0; c < 4; ++c)
                accF[m][c] = __builtin_amdgcn_mfma_f32_16x16x32_bf16(a, bc[c], accF[m][c], 0, 0, 0);
        }
        if (ks < 7) {
            CVT4()
            if (ks < 6) LOADF(bbaseF, ks + 2)
        }
    }

    // ---- stage children h into freed A-row LDS region (per-wave, async) ----
    __syncthreads();   // everyone done reading A-rows
    float sU4[4], sL4[4], sF4[4];
    {
        char* stBase = smem + w * 15360;   // 60 rows x 256 B per wave
        #pragma unroll
        for (int n = 0; n < 6; ++n) {
            #pragma unroll
            for (int j = 0; j < 10; ++j) {
                const float* g = out + ((n * kB + b) * kHID + j) * kHW + hw0 + w * 64 + ln;
                __builtin_amdgcn_global_load_lds(
                    (const __attribute__((address_space(1))) unsigned*)g,
                    (__attribute__((address_space(3))) unsigned*)(stBase + (n * 10 + j) * 256),
                    4, 0, 0);
            }
        }
        // seg prefetch rides the stage's latency shadow (independent VMEM loads)
        #pragma unroll
        for (int ct = 0; ct < 4; ++ct) {
            const int px = col0 + ct * 16;
            sU4[ct] = seg_h[(b * 3 + 1) * kHW + px];
            sL4[ct] = seg_h[(b * 3 + 2) * kHW + px];
            sF4[ct] = seg_f[(b * 2 + 1) * kHW + px];
        }
        asm volatile("s_waitcnt vmcnt(0)" ::: "memory");
        __builtin_amdgcn_sched_barrier(0);
    }
    const float* stW = (const float*)(smem + w * 15360);   // [60][64] fp32

    // ---- unified epilogue ----
    #pragma unroll
    for (int ct = 0; ct < 4; ++ct) {
        const int px = col0 + ct * 16;
        const int ix = lr + ct * 16;       // this lane's px within the wave's 64

        const float sU = sU4[ct];
        const float sL = sL4[ct];
        const float sF = sF4[ct];

        float hsU[10], hsL[10];
        #pragma unroll
        for (int j = 0; j < 10; ++j) {
            hsU[j] = stW[(0 * 10 + j) * 64 + ix] + stW[(1 * 10 + j) * 64 + ix]
                   + stW[(2 * 10 + j) * 64 + ix] + stW[(3 * 10 + j) * 64 + ix];
            hsL[j] = stW[(4 * 10 + j) * 64 + ix] + stW[(5 * 10 + j) * 64 + ix];
        }

        float ucv[3] = {0.f, 0.f, 0.f};

        #pragma unroll
        for (int m = 0; m < 5; ++m) {
            const int t = m * 4 + lg;
            if (t < 10) {
                float ai = acc[m][ct][0] + sideU[(t * 4 + 0) * 11] * sU;
                float ag = acc[m][ct][1] + sideU[(t * 4 + 1) * 11] * sU;
                const float pf = acc[m][ct][2] + sideU[(t * 4 + 2) * 11] * sU;
                float cs = 0.f;
                #pragma unroll
                for (int n = 0; n < 4; ++n) {
                    float fh = pf;
                    #pragma unroll
                    for (int j = 0; j < 10; ++j)
                        fh = fmaf(sideU[(t * 4 + 2) * 11 + 1 + j],
                                  stW[(n * 10 + j) * 64 + ix], fh);
                    const float cv = out[(((9 + n) * kB + b) * kHID + t) * kHW + px];
                    cs = fmaf(sigm(fh), cv, cs);
                }
                #pragma unroll
                for (int j = 0; j < 10; ++j) {
                    ai = fmaf(sideU[(t * 4 + 0) * 11 + 1 + j], hsU[j], ai);
                    ag = fmaf(sideU[(t * 4 + 1) * 11 + 1 + j], hsU[j], ag);
                }
                const float uc = sigm(ai) * tanh_(ag) + cs;
                out[((15 * kB + b) * kHID + t) * kHW + px] = uc;
                if (m < 3) ucv[m] = uc;
            } else {
                const int q = t - 10;
                float ai = acc[m][ct][0] + sideU[(t * 4 + 0) * 11] * sL;
                float ag = acc[m][ct][1] + sideU[(t * 4 + 1) * 11] * sL;
                float ao = acc[m][ct][2] + sideU[(t * 4 + 2) * 11] * sL;
                const float pf = acc[m][ct][3] + sideU[(t * 4 + 3) * 11] * sL;
                float cs = 0.f;
                #pragma unroll
                for (int n = 4; n < 6; ++n) {
                    float fh = pf;
                    #pragma unroll
                    for (int j = 0; j < 10; ++j)
                        fh = fmaf(sideU[(t * 4 + 3) * 11 + 1 + j],
                                  stW[(n * 10 + j) * 64 + ix], fh);
                    const float cv = out[(((9 + n) * kB + b) * kHID + q) * kHW + px];
                    cs = fmaf(sigm(fh), cv, cs);
                }
                #pragma unroll
                for (int j = 0; j < 10; ++j) {
                    ai = fmaf(sideU[(t * 4 + 0) * 11 + 1 + j], hsL[j], ai);
                    ag = fmaf(sideU[(t * 4 + 1) * 11 + 1 + j], hsL[j], ag);
                    ao = fmaf(sideU[(t * 4 + 2) * 11 + 1 + j], hsL[j], ao);
                }
                const float lcv = sigm(ai) * tanh_(ag) + cs;
                const float lhv = sigm(ao) * tanh_(lcv);
                out[((6 * kB + b) * kHID + q) * kHW + px]  = lhv;
                out[((7 * kB + b) * kHID + q) * kHW + px]  = lhv;
                out[((16 * kB + b) * kHID + q) * kHW + px] = lcv;
                xch[q]      = lhv;
                xch[10 + q] = lcv;
            }
        }

        asm volatile("s_waitcnt lgkmcnt(0)" ::: "memory");
        __builtin_amdgcn_sched_barrier(0);

        float lhx[10];
        #pragma unroll
        for (int j = 0; j < 10; ++j) lhx[j] = xch[j];

        #pragma unroll
        for (int mf = 0; mf < 3; ++mf) {
            const int t = mf * 4 + lg;
            if (t < 10) {
                float ai = accF[mf][ct][0] + sideF[(t * 4 + 0) * 11] * sF;
                float ag = accF[mf][ct][1] + sideF[(t * 4 + 1) * 11] * sF;
                float ao = accF[mf][ct][2] + sideF[(t * 4 + 2) * 11] * sF;
                float fh = accF[mf][ct][3] + sideF[(t * 4 + 3) * 11] * sF;
                #pragma unroll
                for (int j = 0; j < 10; ++j) {
                    ai = fmaf(sideF[(t * 4 + 0) * 11 + 1 + j], lhx[j], ai);
                    ag = fmaf(sideF[(t * 4 + 1) * 11 + 1 + j], lhx[j], ag);
                    ao = fmaf(sideF[(t * 4 + 2) * 11 + 1 + j], lhx[j], ao);
                    fh = fmaf(sideF[(t * 4 + 3) * 11 + 1 + j], lhx[j], fh);
                }
                const float lcx = xch[10 + t];
                const float cf = sigm(ai) * tanh_(ag) + sigm(fh) * (ucv[mf] + lcx);
                const float hv = sigm(ao) * tanh_(cf);
                out[((8 * kB + b) * kHID + t) * kHW + px]  = hv;
                out[((17 * kB + b) * kHID + t) * kHW + px] = cf;
            }
        }
    }
}

}  // namespace

extern "C" void kernel_launch(void* const* d_in, const int* in_sizes, int n_in,
                              void* d_out, int out_size, void* d_ws, size_t ws_size,
                              hipStream_t stream) {
    const float* seg_p   = (const float*)d_in[0];
    const float* seg_h   = (const float*)d_in[1];
    const float* seg_f   = (const float*)d_in[2];
    const float* p_fea   = (const float*)d_in[3];
    const float* h_fea   = (const float*)d_in[4];
    const float* f_fea   = (const float*)d_in[5];
    const float* W_leaf  = (const float*)d_in[6];
    const float* W_up    = (const float*)d_in[7];
    const float* Wf_up   = (const float*)d_in[8];
    const float* W_low   = (const float*)d_in[9];
    const float* Wf_low  = (const float*)d_in[10];
    const float* W_full  = (const float*)d_in[11];
    const float* Wf_full = (const float*)d_in[12];
    float* out = (float*)d_out;

    // fused kernel uses >64 KB dynamic LDS
    (void)hipFuncSetAttribute(reinterpret_cast<const void*>(k_uplow_full_mfma),
                              hipFuncAttributeMaxDynamicSharedMemorySize, kLdsBytesUF);

    hipLaunchKernelGGL(k_leaf_mfma, dim3(768), dim3(256), kLdsBytesL, stream,
                       p_fea, seg_p, W_leaf, out);
    hipLaunchKernelGGL(k_uplow_full_mfma, dim3(512), dim3(256), kLdsBytesUF, stream,
                       h_fea, f_fea, seg_h, seg_f,
                       W_up, Wf_up, W_low, Wf_low, W_full, Wf_full, out);
}